// Round 2
// baseline (277.735 us; speedup 1.0000x reference)
//
#include <hip/hip_runtime.h>
#include <math.h>

#define N 8192
#define WSP (80*N)          // per-attend workspace floats
#define OFF_G (8*N)         // g[m][8]
#define OFF_T (16*N)        // vb fp32 (prep) -> per-chunk bf16 hi/lo tiles (rownorm)
// tile layout after rownorm: per 32-row chunk b (floats [OFF_T+2048b, +2048)):
//   ushort tileH[64][32] (A-frag rows: tile[c][kk] = vt[n0+kk][c]), then ushort tileL[64][32]

typedef __attribute__((ext_vector_type(8))) short bf16x8;
typedef __attribute__((ext_vector_type(4))) float f32x4;

#if defined(__has_builtin)
#  if __has_builtin(__builtin_amdgcn_exp2f)
#    define EXP2(x) __builtin_amdgcn_exp2f(x)
#  endif
#endif
#ifndef EXP2
#  define EXP2(x) exp2f(x)
#endif

__device__ __forceinline__ unsigned short bf_hi(float x) {
    union { float f; unsigned u; } v; v.f = x;
    unsigned r = v.u + 0x7fffu + ((v.u >> 16) & 1u);   // round-to-nearest-even
    return (unsigned short)(r >> 16);
}
__device__ __forceinline__ float bf_f(unsigned short h) {
    union { float f; unsigned u; } v; v.u = ((unsigned)h) << 16;
    return v.f;
}

// XCD-segregation: model block->XCD as (lin % 8). Put attend 0 on XCDs 0-3,
// attend 1 on XCDs 4-7 so each XCD's L2 holds ONE attend's hot set (2.5 MB < 4 MB).
// Bijective: lin = (a*4 + (idx&3)) + 8*(idx>>2). Correct under ANY real mapping.
__device__ __forceinline__ void xcd_map(int lin, int& a, int& idx) {
    int xcd = lin & 7;
    a   = xcd >> 2;
    idx = (xcd & 3) | ((lin >> 3) << 2);
}

// ---------------------------------------------------------------------------
// Kernel 0: projections. f is pre-scaled by log2(e) so attention exps are
// bare v_exp_f32 (exp2) downstream.
// ---------------------------------------------------------------------------
__global__ __launch_bounds__(256) void prep_kernel(
    const float* __restrict__ x1, const float* __restrict__ x2,
    const float* __restrict__ Wf, const float* __restrict__ bf,
    const float* __restrict__ Wg, const float* __restrict__ bg,
    const float* __restrict__ Wh1, const float* __restrict__ bh1,
    const float* __restrict__ Wh2, const float* __restrict__ bh2,
    float* __restrict__ ws)
{
    int a, bidx;
    xcd_map(blockIdx.x + (int)gridDim.x * blockIdx.y, a, bidx);   // lin 0..255
    const float* x  = a ? x2  : x1;
    const float* Wh = a ? Wh2 : Wh1;
    const float* bh = a ? bh2 : bh1;
    float* f2 = ws + (size_t)a * WSP;   // [N][8], scaled by log2e
    float* gt = f2 + OFF_G;             // [N][8]
    float* vb = f2 + OFF_T;             // [N][64] fp32 (consumed by rownorm)

    __shared__ float xs[64][65];
    const int n0 = bidx * 64;
    const int t  = threadIdx.x;
    for (int i = t; i < 64*64; i += 256) {
        int c = i >> 6, j = i & 63;
        xs[c][j] = x[(size_t)c*N + n0 + j];
    }
    __syncthreads();

    const int j  = t & 63;
    const int og = t >> 6;
    float s[20];
    const float* wrow[20];
    #pragma unroll
    for (int k = 0; k < 20; ++k) {
        int o = og + 4*k;
        if (o < 8)       { wrow[k] = Wf + o*64;      s[k] = bf[o];      }
        else if (o < 16) { wrow[k] = Wg + (o-8)*64;  s[k] = bg[o-8];    }
        else             { wrow[k] = Wh + (o-16)*64; s[k] = bh[o-16];   }
    }
    #pragma unroll 8
    for (int c = 0; c < 64; ++c) {
        float xc = xs[c][j];
        #pragma unroll
        for (int k = 0; k < 20; ++k) s[k] += wrow[k][c] * xc;
    }
    const float LOG2E = 1.44269504088896340736f;
    #pragma unroll
    for (int k = 0; k < 20; ++k) {
        int o = og + 4*k;
        if (o < 8)       f2[(size_t)(n0+j)*8  + o]      = s[k] * LOG2E;
        else if (o < 16) gt[(size_t)(n0+j)*8  + (o-8)]  = s[k];
        else             vb[(size_t)(n0+j)*64 + (o-16)] = s[k];
    }
}

// ---------------------------------------------------------------------------
// Kernel 1: per-row softmax denominator l[n] = sum_m exp2(f2[n].g[m]); then
// convert vt = v/l to bf16 hi/lo A-fragment tiles IN PLACE over vb.
// One block per 32-row chunk (owns its tile region exclusively).
// ---------------------------------------------------------------------------
__global__ __launch_bounds__(256) void rownorm_kernel(float* __restrict__ ws)
{
    int a, bidx;
    xcd_map(blockIdx.x + (int)gridDim.x * blockIdx.y, a, bidx);   // lin 0..511
    float* f2 = ws + (size_t)a * WSP;
    float* gg = f2 + OFF_G;
    float* vb = f2 + OFF_T;
    const int n0 = bidx * 32;
    const int t  = threadIdx.x;
    const int w = t >> 6, lane = t & 63;

    __shared__ float vbs[32][64];   // staged v rows (so in-place overwrite is safe)
    __shared__ float fs[256];
    __shared__ float linv[32];

    // vb is read exactly once -> non-temporal, vectorized (don't evict g from L2)
    {
        const f32x4* vp = (const f32x4*)(vb + (size_t)n0*64);
        #pragma unroll
        for (int i = 0; i < 2; ++i) {
            int e4 = t*2 + i;                       // 0..511 float4s = 32x64 floats
            f32x4 v = __builtin_nontemporal_load(vp + e4);
            *(f32x4*)&vbs[e4 >> 4][(e4 & 15) * 4] = v;
        }
    }
    fs[t] = f2[(size_t)n0*8 + t];
    __syncthreads();

    // wave w owns rows n0 + 8w .. +8
    float fr[8][8];
    #pragma unroll
    for (int r = 0; r < 8; ++r)
        #pragma unroll
        for (int i = 0; i < 8; ++i) fr[r][i] = fs[(w*8+r)*8 + i];

    float l[8] = {0,0,0,0,0,0,0,0};
    for (int m = lane; m < N; m += 64) {
        const float4 ga = *(const float4*)(gg + (size_t)m*8);
        const float4 gb = *(const float4*)(gg + (size_t)m*8 + 4);
        #pragma unroll
        for (int r = 0; r < 8; ++r) {
            float s = fr[r][0]*ga.x + fr[r][1]*ga.y + fr[r][2]*ga.z + fr[r][3]*ga.w
                    + fr[r][4]*gb.x + fr[r][5]*gb.y + fr[r][6]*gb.z + fr[r][7]*gb.w;
            l[r] += EXP2(s);
        }
    }
    #pragma unroll
    for (int r = 0; r < 8; ++r) {
        float v = l[r];
        #pragma unroll
        for (int off = 32; off; off >>= 1) v += __shfl_xor(v, off, 64);
        if (lane == 0) linv[w*8 + r] = 1.0f / v;
    }
    __syncthreads();

    // phase 3: thread t -> (c = t&63, k-octet kkg = t>>6); one 16B store per array
    const int c = t & 63, kkg = t >> 6;
    bf16x8 H, L;
    #pragma unroll
    for (int jj = 0; jj < 8; ++jj) {
        int kk = kkg*8 + jj;
        float v = vbs[kk][c] * linv[kk];
        unsigned short h = bf_hi(v);
        H[jj] = (short)h;
        L[jj] = (short)bf_hi(v - bf_f(h));
    }
    unsigned short* tile = (unsigned short*)(f2 + OFF_T) + (size_t)(n0 >> 5) * 4096;
    unsigned short* tp = tile + c*32 + kkg*8;
    *(bf16x8*)tp          = H;
    *(bf16x8*)(tp + 2048) = L;
}

// ---------------------------------------------------------------------------
// Kernel 2: sa[c][m] = sum_n vt[n][c] * exp2(f2[n].g[m]) via MFMA bf16 hi/lo.
// 512 threads = 8 waves; each wave: full 64c x 64m tile, 1/8 of K; 2 waves/SIMD.
// f for each 32-k step is staged through wave-private LDS: ONE coalesced 1KB
// global load per step (issued one iteration ahead) replaces 16 broadcast
// global loads; reads are conflict-free broadcast ds_read_b128 (rows shifted
// by +1 row-slot per 8-row group so the 4 quads hit disjoint banks).
// ---------------------------------------------------------------------------
__global__ __launch_bounds__(512, 2) void attn_kernel(
    const float* __restrict__ x1, const float* __restrict__ x2,
    const float* __restrict__ ga1, const float* __restrict__ ga2,
    const float* __restrict__ ws, float* __restrict__ out_)
{
    int a, bidx;
    xcd_map(blockIdx.x + (int)gridDim.x * blockIdx.y, a, bidx);   // lin 0..255
    const float* x = a ? x2 : x1;
    const float gamma = a ? ga2[0] : ga1[0];
    const float* f2 = ws + (size_t)a * WSP;
    const float* gg = f2 + OFF_G;
    const unsigned short* tiles = (const unsigned short*)(f2 + OFF_T);
    float* out = out_ + (size_t)a * ((size_t)64 * N);

    const int m0 = bidx * 64;
    const int t = threadIdx.x;
    const int w = t >> 6, lane = t & 63;
    const int quad = lane >> 4, l15 = lane & 15;

    // per-wave f staging: row r (0..31) of 8 floats at dword 8*(r + (r>>3))
    // -> quad q reads rows q*8+s at 72q+8s: bank( 8q + 16u ) distinct per quad.
    __shared__ __align__(16) float fst[8][288];

    // g fragments: lane's 4 m-columns, resident all kernel
    float4 gA[4], gB[4];
    #pragma unroll
    for (int mt = 0; mt < 4; ++mt) {
        const float* gp = gg + (size_t)(m0 + mt*16 + l15) * 8;
        gA[mt] = *(const float4*)gp;
        gB[mt] = *(const float4*)(gp + 4);
    }

    f32x4 acc[4][4];   // [ct][mt]
    #pragma unroll
    for (int i = 0; i < 4; ++i)
        #pragma unroll
        for (int k = 0; k < 4; ++k) acc[i][k] = (f32x4){0.f,0.f,0.f,0.f};

    const int kbeg = w * (N/8);
    const int kend = kbeg + (N/8);

    union BU { bf16x8 v; unsigned u[4]; };

    const int rr = lane >> 1;                       // staging row this lane writes
    const int soff = 8*(rr + (rr >> 3)) + (lane & 1)*4;

    // prologue: stage f(kbeg)
    {
        const float4 fv = *(const float4*)(f2 + (size_t)kbeg*8 + lane*4);
        *(float4*)&fst[w][soff] = fv;
    }

    for (int k0 = kbeg; k0 < kend; k0 += 32) {
        // issue next step's f load NOW; its vmcnt drains at the ds_write below
        const int kn = (k0 + 32 < kend) ? (k0 + 32) : kbeg;
        const float4 fnext = *(const float4*)(f2 + (size_t)kn*8 + lane*4);

        // A fragments: 4 c-tiles, hi+lo
        bf16x8 Ah[4], Al[4];
        {
            const unsigned short* tb = tiles + (size_t)(k0 >> 5) * 4096 + quad*8;
            #pragma unroll
            for (int ct = 0; ct < 4; ++ct) {
                const unsigned short* tc = tb + (ct*16 + l15) * 32;
                Ah[ct] = *(const bf16x8*)tc;
                Al[ct] = *(const bf16x8*)(tc + 2048);
            }
        }
        // B fragments: p = exp2(f.g) in B layout, truncation hi/lo split.
        // f rows come from wave-private LDS (broadcast within each quad).
        BU bh[4], bl[4];
        {
            const float* fw = &fst[w][72*quad];
            #pragma unroll
            for (int u = 0; u < 4; ++u) {
                const float4 f0a = *(const float4*)(fw + 16*u);
                const float4 f0b = *(const float4*)(fw + 16*u + 4);
                const float4 f1a = *(const float4*)(fw + 16*u + 8);
                const float4 f1b = *(const float4*)(fw + 16*u + 12);
                #pragma unroll
                for (int mt = 0; mt < 4; ++mt) {
                    float s0 = f0a.x*gA[mt].x + f0a.y*gA[mt].y + f0a.z*gA[mt].z + f0a.w*gA[mt].w
                             + f0b.x*gB[mt].x + f0b.y*gB[mt].y + f0b.z*gB[mt].z + f0b.w*gB[mt].w;
                    float s1 = f1a.x*gA[mt].x + f1a.y*gA[mt].y + f1a.z*gA[mt].z + f1a.w*gA[mt].w
                             + f1b.x*gB[mt].x + f1b.y*gB[mt].y + f1b.z*gB[mt].z + f1b.w*gB[mt].w;
                    float p0 = EXP2(s0), p1 = EXP2(s1);
                    unsigned i0 = __float_as_uint(p0), i1 = __float_as_uint(p1);
                    bh[mt].u[u] = (i1 & 0xffff0000u) | (i0 >> 16);
                    float r0 = p0 - __uint_as_float(i0 & 0xffff0000u);
                    float r1 = p1 - __uint_as_float(i1 & 0xffff0000u);
                    bl[mt].u[u] = (__float_as_uint(r1) & 0xffff0000u)
                                | (__float_as_uint(r0) >> 16);
                }
            }
        }
        #pragma unroll
        for (int mt = 0; mt < 4; ++mt) {
            #pragma unroll
            for (int ct = 0; ct < 4; ++ct) {
                acc[ct][mt] = __builtin_amdgcn_mfma_f32_16x16x32_bf16(Ah[ct], bh[mt].v, acc[ct][mt], 0, 0, 0);
                acc[ct][mt] = __builtin_amdgcn_mfma_f32_16x16x32_bf16(Ah[ct], bl[mt].v, acc[ct][mt], 0, 0, 0);
                acc[ct][mt] = __builtin_amdgcn_mfma_f32_16x16x32_bf16(Al[ct], bh[mt].v, acc[ct][mt], 0, 0, 0);
            }
        }
        // stage next step's f AFTER this step's reads (in-order DS per wave;
        // compiler preserves order through may-alias on fst)
        *(float4*)&fst[w][soff] = fnext;
    }

    // cross-wave (K-split) reduction over 8 waves
    __shared__ float red[64][65];
    for (int ww = 0; ww < 8; ++ww) {
        if (w == ww) {
            #pragma unroll
            for (int ct = 0; ct < 4; ++ct)
                #pragma unroll
                for (int mt = 0; mt < 4; ++mt)
                    #pragma unroll
                    for (int r = 0; r < 4; ++r) {
                        int c = ct*16 + quad*4 + r;      // C/D: row=(lane>>4)*4+reg
                        int m = mt*16 + l15;             //      col=lane&15
                        if (ww == 0) red[c][m]  = acc[ct][mt][r];
                        else         red[c][m] += acc[ct][mt][r];
                    }
        }
        __syncthreads();
    }
    #pragma unroll
    for (int i = 0; i < 8; ++i) {
        int e = t + 512*i;
        int c = e >> 6, m = e & 63;
        size_t gi = (size_t)c*N + m0 + m;
        float xv = __builtin_nontemporal_load(x + gi);
        __builtin_nontemporal_store(gamma * red[c][m] + xv, out + gi);
    }
}

// ---------------------------------------------------------------------------
extern "C" void kernel_launch(void* const* d_in, const int* in_sizes, int n_in,
                              void* d_out, int out_size, void* d_ws, size_t ws_size,
                              hipStream_t stream)
{
    (void)in_sizes; (void)n_in; (void)out_size; (void)ws_size;
    const float* x1  = (const float*)d_in[0];
    const float* x2  = (const float*)d_in[1];
    const float* Wf  = (const float*)d_in[2];
    const float* bf  = (const float*)d_in[3];
    const float* Wg  = (const float*)d_in[4];
    const float* bg  = (const float*)d_in[5];
    const float* Wh1 = (const float*)d_in[6];
    const float* bh1 = (const float*)d_in[7];
    const float* Wh2 = (const float*)d_in[8];
    const float* bh2 = (const float*)d_in[9];
    const float* g1  = (const float*)d_in[10];
    const float* g2  = (const float*)d_in[11];
    float* out = (float*)d_out;
    float* ws  = (float*)d_ws;

    prep_kernel   <<<dim3(N/64, 2), dim3(256), 0, stream>>>(x1,x2,Wf,bf,Wg,bg,Wh1,bh1,Wh2,bh2,ws);
    rownorm_kernel<<<dim3(N/32, 2), dim3(256), 0, stream>>>(ws);
    attn_kernel   <<<dim3(N/64, 2), dim3(512), 0, stream>>>(x1,x2,g1,g2,ws,out);
}

// Round 3
// 261.710 us; speedup vs baseline: 1.0612x; 1.0612x over previous
//
#include <hip/hip_runtime.h>
#include <math.h>

#define N 8192
#define WSP (80*N)          // per-attend workspace floats
#define OFF_G (8*N)         // g[m][8]
#define OFF_T (16*N)        // vb fp32 (prep) -> per-chunk bf16 hi/lo tiles (rownorm)
// tile layout after rownorm: per 32-row chunk b (floats [OFF_T+2048b, +2048)):
//   ushort tileH[64][32] (A-frag rows: tile[c][kk] = vt[n0+kk][c]), then ushort tileL[64][32]

typedef __attribute__((ext_vector_type(8))) short bf16x8;
typedef __attribute__((ext_vector_type(4))) float f32x4;

#if defined(__has_builtin)
#  if __has_builtin(__builtin_amdgcn_exp2f)
#    define EXP2(x) __builtin_amdgcn_exp2f(x)
#  endif
#endif
#ifndef EXP2
#  define EXP2(x) exp2f(x)
#endif

__device__ __forceinline__ unsigned short bf_hi(float x) {
    union { float f; unsigned u; } v; v.f = x;
    unsigned r = v.u + 0x7fffu + ((v.u >> 16) & 1u);   // round-to-nearest-even
    return (unsigned short)(r >> 16);
}
__device__ __forceinline__ float bf_f(unsigned short h) {
    union { float f; unsigned u; } v; v.u = ((unsigned)h) << 16;
    return v.f;
}

// XCD-segregation: model block->XCD as (lin % 8). Put attend 0 on XCDs 0-3,
// attend 1 on XCDs 4-7 so each XCD's L2 holds ONE attend's hot set.
// Bijective for lin ranges that are multiples of 8.
__device__ __forceinline__ void xcd_map(int lin, int& a, int& idx) {
    int xcd = lin & 7;
    a   = xcd >> 2;
    idx = (xcd & 3) | ((lin >> 3) << 2);
}

// ---------------------------------------------------------------------------
// Kernel 0: projections. f is pre-scaled by log2(e) so attention exps are
// bare v_exp_f32 (exp2) downstream.
// ---------------------------------------------------------------------------
__global__ __launch_bounds__(256) void prep_kernel(
    const float* __restrict__ x1, const float* __restrict__ x2,
    const float* __restrict__ Wf, const float* __restrict__ bf,
    const float* __restrict__ Wg, const float* __restrict__ bg,
    const float* __restrict__ Wh1, const float* __restrict__ bh1,
    const float* __restrict__ Wh2, const float* __restrict__ bh2,
    float* __restrict__ ws)
{
    int a, bidx;
    xcd_map(blockIdx.x + (int)gridDim.x * blockIdx.y, a, bidx);   // lin 0..255
    const float* x  = a ? x2  : x1;
    const float* Wh = a ? Wh2 : Wh1;
    const float* bh = a ? bh2 : bh1;
    float* f2 = ws + (size_t)a * WSP;   // [N][8], scaled by log2e
    float* gt = f2 + OFF_G;             // [N][8]
    float* vb = f2 + OFF_T;             // [N][64] fp32 (consumed by rownorm)

    __shared__ float xs[64][65];
    const int n0 = bidx * 64;
    const int t  = threadIdx.x;
    for (int i = t; i < 64*64; i += 256) {
        int c = i >> 6, j = i & 63;
        xs[c][j] = x[(size_t)c*N + n0 + j];
    }
    __syncthreads();

    const int j  = t & 63;
    const int og = t >> 6;
    float s[20];
    const float* wrow[20];
    #pragma unroll
    for (int k = 0; k < 20; ++k) {
        int o = og + 4*k;
        if (o < 8)       { wrow[k] = Wf + o*64;      s[k] = bf[o];      }
        else if (o < 16) { wrow[k] = Wg + (o-8)*64;  s[k] = bg[o-8];    }
        else             { wrow[k] = Wh + (o-16)*64; s[k] = bh[o-16];   }
    }
    #pragma unroll 8
    for (int c = 0; c < 64; ++c) {
        float xc = xs[c][j];
        #pragma unroll
        for (int k = 0; k < 20; ++k) s[k] += wrow[k][c] * xc;
    }
    const float LOG2E = 1.44269504088896340736f;
    #pragma unroll
    for (int k = 0; k < 20; ++k) {
        int o = og + 4*k;
        if (o < 8)       f2[(size_t)(n0+j)*8  + o]      = s[k] * LOG2E;
        else if (o < 16) gt[(size_t)(n0+j)*8  + (o-8)]  = s[k];
        else             vb[(size_t)(n0+j)*64 + (o-16)] = s[k];
    }
}

// ---------------------------------------------------------------------------
// Kernel 1: per-row softmax denominator l[n] = sum_m exp2(f2[n].g[m]); then
// convert vt = v/l to bf16 hi/lo A-fragment tiles IN PLACE over vb.
// 512 threads = 8 waves; wave w owns 4 rows (vs 8 before) -> 16 waves/CU and
// m-loop unrolled x2 (4 independent float4 loads in flight) for latency hiding.
// ---------------------------------------------------------------------------
__global__ __launch_bounds__(512, 4) void rownorm_kernel(float* __restrict__ ws)
{
    int a, bidx;
    xcd_map(blockIdx.x + (int)gridDim.x * blockIdx.y, a, bidx);   // lin 0..511
    float* f2 = ws + (size_t)a * WSP;
    float* gg = f2 + OFF_G;
    float* vb = f2 + OFF_T;
    const int n0 = bidx * 32;
    const int t  = threadIdx.x;
    const int w = t >> 6, lane = t & 63;

    __shared__ float vbs[32][64];   // staged v rows (so in-place overwrite is safe)
    __shared__ float fs[256];
    __shared__ float linv[32];

    // vb is read exactly once -> non-temporal, vectorized; 512 x 16B = 8 KB
    {
        const f32x4* vp = (const f32x4*)(vb + (size_t)n0*64);
        f32x4 v = __builtin_nontemporal_load(vp + t);
        *(f32x4*)&vbs[t >> 4][(t & 15) * 4] = v;
    }
    if (t < 256) fs[t] = f2[(size_t)n0*8 + t];
    __syncthreads();

    // wave w owns rows n0 + 4w .. +4
    float fr[4][8];
    #pragma unroll
    for (int r = 0; r < 4; ++r)
        #pragma unroll
        for (int i = 0; i < 8; ++i) fr[r][i] = fs[(w*4+r)*8 + i];

    float l[4] = {0,0,0,0};
    for (int m = lane; m < N; m += 128) {
        const float4 ga0 = *(const float4*)(gg + (size_t)m*8);
        const float4 gb0 = *(const float4*)(gg + (size_t)m*8 + 4);
        const float4 ga1 = *(const float4*)(gg + (size_t)(m+64)*8);
        const float4 gb1 = *(const float4*)(gg + (size_t)(m+64)*8 + 4);
        #pragma unroll
        for (int r = 0; r < 4; ++r) {
            float s0 = fr[r][0]*ga0.x + fr[r][1]*ga0.y + fr[r][2]*ga0.z + fr[r][3]*ga0.w
                     + fr[r][4]*gb0.x + fr[r][5]*gb0.y + fr[r][6]*gb0.z + fr[r][7]*gb0.w;
            float s1 = fr[r][0]*ga1.x + fr[r][1]*ga1.y + fr[r][2]*ga1.z + fr[r][3]*ga1.w
                     + fr[r][4]*gb1.x + fr[r][5]*gb1.y + fr[r][6]*gb1.z + fr[r][7]*gb1.w;
            l[r] += EXP2(s0) + EXP2(s1);
        }
    }
    #pragma unroll
    for (int r = 0; r < 4; ++r) {
        float v = l[r];
        #pragma unroll
        for (int off = 32; off; off >>= 1) v += __shfl_xor(v, off, 64);
        if (lane == 0) linv[w*4 + r] = 1.0f / v;
    }
    __syncthreads();

    // phase 3: threads 0..255 -> (c = t&63, k-octet kkg = t>>6); 16B stores
    if (t < 256) {
        const int c = t & 63, kkg = t >> 6;
        bf16x8 H, L;
        #pragma unroll
        for (int jj = 0; jj < 8; ++jj) {
            int kk = kkg*8 + jj;
            float v = vbs[kk][c] * linv[kk];
            unsigned short h = bf_hi(v);
            H[jj] = (short)h;
            L[jj] = (short)bf_hi(v - bf_f(h));
        }
        unsigned short* tile = (unsigned short*)(f2 + OFF_T) + (size_t)(n0 >> 5) * 4096;
        unsigned short* tp = tile + c*32 + kkg*8;
        *(bf16x8*)tp          = H;
        *(bf16x8*)(tp + 2048) = L;
    }
}

// ---------------------------------------------------------------------------
// Kernel 2: sa[c][m] = sum_n vt[n][c] * exp2(f2[n].g[m]) via MFMA bf16 hi/lo.
// m-tile 32 (was 64) -> 512 blocks -> 2 blocks/CU = 16 waves/CU for latency
// hiding. 8 waves; each wave: 64c x 32m tile, 1/8 of K. f staged per-wave in
// LDS (one coalesced load/step issued one iteration ahead).
// ---------------------------------------------------------------------------
__global__ __launch_bounds__(512, 4) void attn_kernel(
    const float* __restrict__ x1, const float* __restrict__ x2,
    const float* __restrict__ ga1, const float* __restrict__ ga2,
    const float* __restrict__ ws, float* __restrict__ out_)
{
    int a, bidx;
    xcd_map(blockIdx.x + (int)gridDim.x * blockIdx.y, a, bidx);   // lin 0..511
    const float* x = a ? x2 : x1;
    const float gamma = a ? ga2[0] : ga1[0];
    const float* f2 = ws + (size_t)a * WSP;
    const float* gg = f2 + OFF_G;
    const unsigned short* tiles = (const unsigned short*)(f2 + OFF_T);
    float* out = out_ + (size_t)a * ((size_t)64 * N);

    const int m0 = bidx * 32;
    const int t = threadIdx.x;
    const int w = t >> 6, lane = t & 63;
    const int quad = lane >> 4, l15 = lane & 15;

    // per-wave f staging: row r (0..31) of 8 floats at dword 8*(r + (r>>3))
    // -> quad q reads rows q*8+s at 72q+8s: banks distinct per quad.
    __shared__ __align__(16) float fst[8][288];

    // g fragments: lane's 2 m-columns, resident all kernel
    float4 gA[2], gB[2];
    #pragma unroll
    for (int mt = 0; mt < 2; ++mt) {
        const float* gp = gg + (size_t)(m0 + mt*16 + l15) * 8;
        gA[mt] = *(const float4*)gp;
        gB[mt] = *(const float4*)(gp + 4);
    }

    f32x4 acc[4][2];   // [ct][mt]
    #pragma unroll
    for (int i = 0; i < 4; ++i)
        #pragma unroll
        for (int k = 0; k < 2; ++k) acc[i][k] = (f32x4){0.f,0.f,0.f,0.f};

    const int kbeg = w * (N/8);
    const int kend = kbeg + (N/8);

    union BU { bf16x8 v; unsigned u[4]; };

    const int rr = lane >> 1;                       // staging row this lane writes
    const int soff = 8*(rr + (rr >> 3)) + (lane & 1)*4;

    // prologue: stage f(kbeg)
    {
        const float4 fv = *(const float4*)(f2 + (size_t)kbeg*8 + lane*4);
        *(float4*)&fst[w][soff] = fv;
    }

    for (int k0 = kbeg; k0 < kend; k0 += 32) {
        // issue next step's f load NOW; its vmcnt drains at the ds_write below
        const int kn = (k0 + 32 < kend) ? (k0 + 32) : kbeg;
        const float4 fnext = *(const float4*)(f2 + (size_t)kn*8 + lane*4);

        // A fragments: 4 c-tiles, hi+lo
        bf16x8 Ah[4], Al[4];
        {
            const unsigned short* tb = tiles + (size_t)(k0 >> 5) * 4096 + quad*8;
            #pragma unroll
            for (int ct = 0; ct < 4; ++ct) {
                const unsigned short* tc = tb + (ct*16 + l15) * 32;
                Ah[ct] = *(const bf16x8*)tc;
                Al[ct] = *(const bf16x8*)(tc + 2048);
            }
        }
        // B fragments: p = exp2(f.g) in B layout, truncation hi/lo split.
        // f rows come from wave-private LDS (broadcast within each quad).
        BU bh[2], bl[2];
        {
            const float* fw = &fst[w][72*quad];
            #pragma unroll
            for (int u = 0; u < 4; ++u) {
                const float4 f0a = *(const float4*)(fw + 16*u);
                const float4 f0b = *(const float4*)(fw + 16*u + 4);
                const float4 f1a = *(const float4*)(fw + 16*u + 8);
                const float4 f1b = *(const float4*)(fw + 16*u + 12);
                #pragma unroll
                for (int mt = 0; mt < 2; ++mt) {
                    float s0 = f0a.x*gA[mt].x + f0a.y*gA[mt].y + f0a.z*gA[mt].z + f0a.w*gA[mt].w
                             + f0b.x*gB[mt].x + f0b.y*gB[mt].y + f0b.z*gB[mt].z + f0b.w*gB[mt].w;
                    float s1 = f1a.x*gA[mt].x + f1a.y*gA[mt].y + f1a.z*gA[mt].z + f1a.w*gA[mt].w
                             + f1b.x*gB[mt].x + f1b.y*gB[mt].y + f1b.z*gB[mt].z + f1b.w*gB[mt].w;
                    float p0 = EXP2(s0), p1 = EXP2(s1);
                    unsigned i0 = __float_as_uint(p0), i1 = __float_as_uint(p1);
                    bh[mt].u[u] = (i1 & 0xffff0000u) | (i0 >> 16);
                    float r0 = p0 - __uint_as_float(i0 & 0xffff0000u);
                    float r1 = p1 - __uint_as_float(i1 & 0xffff0000u);
                    bl[mt].u[u] = (__float_as_uint(r1) & 0xffff0000u)
                                | (__float_as_uint(r0) >> 16);
                }
            }
        }
        #pragma unroll
        for (int mt = 0; mt < 2; ++mt) {
            #pragma unroll
            for (int ct = 0; ct < 4; ++ct) {
                acc[ct][mt] = __builtin_amdgcn_mfma_f32_16x16x32_bf16(Ah[ct], bh[mt].v, acc[ct][mt], 0, 0, 0);
                acc[ct][mt] = __builtin_amdgcn_mfma_f32_16x16x32_bf16(Ah[ct], bl[mt].v, acc[ct][mt], 0, 0, 0);
                acc[ct][mt] = __builtin_amdgcn_mfma_f32_16x16x32_bf16(Al[ct], bh[mt].v, acc[ct][mt], 0, 0, 0);
            }
        }
        // stage next step's f AFTER this step's reads (in-order DS per wave)
        *(float4*)&fst[w][soff] = fnext;
    }

    // cross-wave (K-split) reduction over 8 waves
    __shared__ float red[64][33];
    for (int ww = 0; ww < 8; ++ww) {
        if (w == ww) {
            #pragma unroll
            for (int ct = 0; ct < 4; ++ct)
                #pragma unroll
                for (int mt = 0; mt < 2; ++mt)
                    #pragma unroll
                    for (int r = 0; r < 4; ++r) {
                        int c = ct*16 + quad*4 + r;      // C/D: row=(lane>>4)*4+reg
                        int m = mt*16 + l15;             //      col=lane&15
                        if (ww == 0) red[c][m]  = acc[ct][mt][r];
                        else         red[c][m] += acc[ct][mt][r];
                    }
        }
        __syncthreads();
    }
    #pragma unroll
    for (int i = 0; i < 4; ++i) {
        int e = t + 512*i;
        int c = e >> 5, m = e & 31;
        size_t gi = (size_t)c*N + m0 + m;
        float xv = __builtin_nontemporal_load(x + gi);
        __builtin_nontemporal_store(gamma * red[c][m] + xv, out + gi);
    }
}

// ---------------------------------------------------------------------------
extern "C" void kernel_launch(void* const* d_in, const int* in_sizes, int n_in,
                              void* d_out, int out_size, void* d_ws, size_t ws_size,
                              hipStream_t stream)
{
    (void)in_sizes; (void)n_in; (void)out_size; (void)ws_size;
    const float* x1  = (const float*)d_in[0];
    const float* x2  = (const float*)d_in[1];
    const float* Wf  = (const float*)d_in[2];
    const float* bf  = (const float*)d_in[3];
    const float* Wg  = (const float*)d_in[4];
    const float* bg  = (const float*)d_in[5];
    const float* Wh1 = (const float*)d_in[6];
    const float* bh1 = (const float*)d_in[7];
    const float* Wh2 = (const float*)d_in[8];
    const float* bh2 = (const float*)d_in[9];
    const float* g1  = (const float*)d_in[10];
    const float* g2  = (const float*)d_in[11];
    float* out = (float*)d_out;
    float* ws  = (float*)d_ws;

    prep_kernel   <<<dim3(N/64, 2), dim3(256), 0, stream>>>(x1,x2,Wf,bf,Wg,bg,Wh1,bh1,Wh2,bh2,ws);
    rownorm_kernel<<<dim3(N/32, 2), dim3(512), 0, stream>>>(ws);
    attn_kernel   <<<dim3(N/32, 2), dim3(512), 0, stream>>>(x1,x2,g1,g2,ws,out);
}

// Round 5
// 198.716 us; speedup vs baseline: 1.3977x; 1.3170x over previous
//
#include <hip/hip_runtime.h>
#include <math.h>

#define N 8192
#define WSP (80*N)          // per-attend workspace floats
#define OFF_G (8*N)         // G bf16 hi/lo [N][16] ushort
#define OFF_T (16*N)        // vb fp32 (prep) -> per-chunk bf16 hi/lo tiles (rownorm)
// F at base: [N][16] ushort = row n: fh[0..7], fl[0..7]  (f pre-scaled by log2e)
// G at OFF_G: same layout for g.
// tiles after rownorm: per 32-row chunk b (4096 ushorts each at OFF_T):
//   ushort tileH[64][32], tileL[64][32]; row c, position q holds vt[n0+sigma(q)][c]
//   with sigma(q) = (q>>4)*16 + (q&3) + 8*((q>>2)&1) + 4*((q>>3)&1)  — the 32x32
//   MFMA C/D row permutation, so exp2(S) packs DIRECTLY into PV B-fragments.

typedef __attribute__((ext_vector_type(8)))  short bf16x8;
typedef __attribute__((ext_vector_type(4)))  float f32x4;
typedef __attribute__((ext_vector_type(16))) float f32x16;

#define ZERO16 ((f32x16){0.f,0.f,0.f,0.f,0.f,0.f,0.f,0.f,0.f,0.f,0.f,0.f,0.f,0.f,0.f,0.f})

#if defined(__has_builtin)
#  if __has_builtin(__builtin_amdgcn_exp2f)
#    define EXP2(x) __builtin_amdgcn_exp2f(x)
#  endif
#endif
#ifndef EXP2
#  define EXP2(x) exp2f(x)
#endif

__device__ __forceinline__ unsigned short bf_hi(float x) {
    union { float f; unsigned u; } v; v.f = x;
    unsigned r = v.u + 0x7fffu + ((v.u >> 16) & 1u);   // round-to-nearest-even
    return (unsigned short)(r >> 16);
}
__device__ __forceinline__ float bf_f(unsigned short h) {
    union { float f; unsigned u; } v; v.u = ((unsigned)h) << 16;
    return v.f;
}

// XCD-segregation: attend 0 on XCDs 0-3, attend 1 on XCDs 4-7.
__device__ __forceinline__ void xcd_map(int lin, int& a, int& idx) {
    int xcd = lin & 7;
    a   = xcd >> 2;
    idx = (xcd & 3) | ((lin >> 3) << 2);
}

// ---------------------------------------------------------------------------
// Kernel 0: projections. f,g stored as bf16 hi/lo MFMA-fragment rows.
// ---------------------------------------------------------------------------
__global__ __launch_bounds__(256) void prep_kernel(
    const float* __restrict__ x1, const float* __restrict__ x2,
    const float* __restrict__ Wf, const float* __restrict__ bf,
    const float* __restrict__ Wg, const float* __restrict__ bg,
    const float* __restrict__ Wh1, const float* __restrict__ bh1,
    const float* __restrict__ Wh2, const float* __restrict__ bh2,
    float* __restrict__ ws)
{
    int a, bidx;
    xcd_map(blockIdx.x + (int)gridDim.x * blockIdx.y, a, bidx);   // lin 0..255
    const float* x  = a ? x2  : x1;
    const float* Wh = a ? Wh2 : Wh1;
    const float* bh = a ? bh2 : bh1;
    float* base = ws + (size_t)a * WSP;
    unsigned short* F16 = (unsigned short*)base;           // [N][16]
    unsigned short* G16 = (unsigned short*)(base + OFF_G); // [N][16]
    float* vb = base + OFF_T;                              // [N][64] fp32

    __shared__ float xs[64][65];
    const int n0 = bidx * 64;
    const int t  = threadIdx.x;
    for (int i = t; i < 64*64; i += 256) {
        int c = i >> 6, j = i & 63;
        xs[c][j] = x[(size_t)c*N + n0 + j];
    }
    __syncthreads();

    const int j  = t & 63;
    const int og = t >> 6;
    float s[20];
    const float* wrow[20];
    #pragma unroll
    for (int k = 0; k < 20; ++k) {
        int o = og + 4*k;
        if (o < 8)       { wrow[k] = Wf + o*64;      s[k] = bf[o];      }
        else if (o < 16) { wrow[k] = Wg + (o-8)*64;  s[k] = bg[o-8];    }
        else             { wrow[k] = Wh + (o-16)*64; s[k] = bh[o-16];   }
    }
    #pragma unroll 8
    for (int c = 0; c < 64; ++c) {
        float xc = xs[c][j];
        #pragma unroll
        for (int k = 0; k < 20; ++k) s[k] += wrow[k][c] * xc;
    }
    const float LOG2E = 1.44269504088896340736f;
    #pragma unroll
    for (int k = 0; k < 20; ++k) {
        int o = og + 4*k;
        if (o < 8) {
            float v = s[k] * LOG2E;
            unsigned short h = bf_hi(v);
            F16[(size_t)(n0+j)*16 + o]     = h;
            F16[(size_t)(n0+j)*16 + 8 + o] = bf_hi(v - bf_f(h));
        } else if (o < 16) {
            float v = s[k];
            unsigned short h = bf_hi(v);
            G16[(size_t)(n0+j)*16 + (o-8)]     = h;
            G16[(size_t)(n0+j)*16 + 8 + (o-8)] = bf_hi(v - bf_f(h));
        } else {
            vb[(size_t)(n0+j)*64 + (o-16)] = s[k];
        }
    }
}

// ---------------------------------------------------------------------------
// Kernel 1: l[n] = sum_m exp2(f[n].g[m]) via 32x32x16 MFMA logits; then
// vt = v/l emitted as bf16 hi/lo tiles with sigma-permuted rows.
// Block = 32 n-rows; 8 waves each own N/8 of m.
// ---------------------------------------------------------------------------
__global__ __launch_bounds__(512, 4) void rownorm_kernel(float* __restrict__ ws)
{
    int a, bidx;
    xcd_map(blockIdx.x + (int)gridDim.x * blockIdx.y, a, bidx);   // lin 0..511
    float* base = ws + (size_t)a * WSP;
    const unsigned short* F16 = (const unsigned short*)base;
    const unsigned short* G16 = (const unsigned short*)(base + OFF_G);
    float* vb = base + OFF_T;
    const int n0 = bidx * 32;
    const int t  = threadIdx.x;
    const int w = t >> 6, lane = t & 63, l31 = lane & 31, hi = lane >> 5;

    __shared__ float vbs[32][64];   // staged v rows (in-place overwrite safety)
    __shared__ float lsum[8][32];
    __shared__ float linv[32];

    {   // vb read exactly once -> non-temporal
        const f32x4* vp = (const f32x4*)(vb + (size_t)n0*64);
        f32x4 v = __builtin_nontemporal_load(vp + t);
        *(f32x4*)&vbs[t >> 4][(t & 15) * 4] = v;
    }

    // A fragment: rows n0..n0+31, hi half = fl octet (3-term hi/lo packing)
    const bf16x8 A1 = *(const bf16x8*)(F16 + (size_t)(n0 + l31)*16 + hi*8);
    const bf16x8 z8 = {0,0,0,0,0,0,0,0};
    const bf16x8 A2 = hi ? z8 : A1;      // [fh ; 0]

    f32x16 sum = ZERO16;
    for (int ms = w*(N/8); ms < (w+1)*(N/8); ms += 32) {
        const bf16x8 B1 = *(const bf16x8*)(G16 + (size_t)(ms + l31)*16);      // [gh;gh]
        const bf16x8 B2 = *(const bf16x8*)(G16 + (size_t)(ms + l31)*16 + 8);  // [gl;gl]
        f32x16 S = __builtin_amdgcn_mfma_f32_32x32x16_bf16(A1, B1, ZERO16, 0, 0, 0);
        S = __builtin_amdgcn_mfma_f32_32x32x16_bf16(A2, B2, S, 0, 0, 0);
        #pragma unroll
        for (int r = 0; r < 16; ++r) sum[r] += EXP2(S[r]);
    }
    // reduce over the 32 m-columns (within each hi half)
    #pragma unroll
    for (int r = 0; r < 16; ++r) {
        float v = sum[r];
        v += __shfl_xor(v, 1, 64);
        v += __shfl_xor(v, 2, 64);
        v += __shfl_xor(v, 4, 64);
        v += __shfl_xor(v, 8, 64);
        v += __shfl_xor(v, 16, 64);
        sum[r] = v;
    }
    if (l31 == 0) {
        #pragma unroll
        for (int r = 0; r < 16; ++r) {
            int n = (r & 3) + 8*(r >> 2) + 4*hi;
            lsum[w][n] = sum[r];
        }
    }
    __syncthreads();
    if (t < 32) {
        float v = 0.f;
        #pragma unroll
        for (int ww = 0; ww < 8; ++ww) v += lsum[ww][t];
        linv[t] = 1.0f / v;
    }
    __syncthreads();

    // emit tiles: position kk holds vt[n0 + sigma(kk)][c]
    if (t < 256) {
        const int c = t & 63, kkg = t >> 6;
        bf16x8 H, L;
        #pragma unroll
        for (int jj = 0; jj < 8; ++jj) {
            int n_rd = (kkg >> 1)*16 + 4*(kkg & 1) + (jj & 3) + 8*((jj >> 2) & 1);
            float v = vbs[n_rd][c] * linv[n_rd];
            unsigned short h = bf_hi(v);
            H[jj] = (short)h;
            L[jj] = (short)bf_hi(v - bf_f(h));
        }
        unsigned short* tile = (unsigned short*)(base + OFF_T) + (size_t)(n0 >> 5) * 4096;
        unsigned short* tp = tile + c*32 + kkg*8;
        *(bf16x8*)tp          = H;
        *(bf16x8*)(tp + 2048) = L;
    }
}

// ---------------------------------------------------------------------------
// Kernel 2: sa[c][m] = sum_n vt[n][c] * exp2(f[n].g[m]).
// Per wave per 32-n step: logits via 2x mfma_32x32x16 (packed hi/lo K=16),
// exp2, truncation hi/lo pack straight into PV B-fragments (sigma-matched
// tiles), then 12x mfma_32x32x16 PV. No per-logit VALU dot products.
// ---------------------------------------------------------------------------
__global__ __launch_bounds__(512, 4) void attn_kernel(
    const float* __restrict__ x1, const float* __restrict__ x2,
    const float* __restrict__ ga1, const float* __restrict__ ga2,
    const float* __restrict__ ws, float* __restrict__ out_)
{
    int a, bidx;
    xcd_map(blockIdx.x + (int)gridDim.x * blockIdx.y, a, bidx);   // lin 0..511
    const float* x = a ? x2 : x1;
    const float gamma = a ? ga2[0] : ga1[0];
    const float* base = ws + (size_t)a * WSP;
    const unsigned short* F16 = (const unsigned short*)base;
    const unsigned short* G16 = (const unsigned short*)(base + OFF_G);
    const unsigned short* tiles = (const unsigned short*)(base + OFF_T);
    float* out = out_ + (size_t)a * ((size_t)64 * N);

    const int m0 = bidx * 32;
    const int t = threadIdx.x;
    const int w = t >> 6, lane = t & 63, l31 = lane & 31, hi = lane >> 5;

    // g fragments for the block's 32 m-columns (resident all kernel)
    const bf16x8 Bh = *(const bf16x8*)(G16 + (size_t)(m0 + l31)*16);          // [gh;gh]
    const bf16x8 Bl_raw = *(const bf16x8*)(G16 + (size_t)(m0 + l31)*16 + 8);
    const bf16x8 z8 = {0,0,0,0,0,0,0,0};
    const bf16x8 Bl = hi ? z8 : Bl_raw;                                        // [gl;0]

    f32x16 acc0 = ZERO16, acc1 = ZERO16;

    for (int ns = w*(N/8); ns < (w+1)*(N/8); ns += 32) {
        // logits S[n=sigma-rows][m]: 2 MFMAs, exact 3-term hi/lo
        const bf16x8 A1 = *(const bf16x8*)(F16 + (size_t)(ns + l31)*16 + hi*8); // [fh;fl]
        f32x16 S = __builtin_amdgcn_mfma_f32_32x32x16_bf16(A1, Bh, ZERO16, 0, 0, 0);
        S = __builtin_amdgcn_mfma_f32_32x32x16_bf16(A1, Bl, S, 0, 0, 0);

        const unsigned short* tb = tiles + (size_t)(ns >> 5) * 4096;
        #pragma unroll
        for (int kp = 0; kp < 2; ++kp) {
            // p = exp2(S) packed into B-fragment (hi + truncation residual)
            union { bf16x8 v; unsigned u[4]; } pH, pL;
            #pragma unroll
            for (int d = 0; d < 4; ++d) {
                float p0 = EXP2(S[kp*8 + 2*d]);
                float p1 = EXP2(S[kp*8 + 2*d + 1]);
                unsigned i0 = __float_as_uint(p0), i1 = __float_as_uint(p1);
                pH.u[d] = (i1 & 0xffff0000u) | (i0 >> 16);
                float r0 = p0 - __uint_as_float(i0 & 0xffff0000u);
                float r1 = p1 - __uint_as_float(i1 & 0xffff0000u);
                pL.u[d] = (__float_as_uint(r1) & 0xffff0000u)
                        | (__float_as_uint(r0) >> 16);
            }
            #pragma unroll
            for (int ct = 0; ct < 2; ++ct) {
                const unsigned short* tc = tb + (ct*32 + l31)*32 + kp*16 + hi*8;
                const bf16x8 AH = *(const bf16x8*)tc;
                const bf16x8 AL = *(const bf16x8*)(tc + 2048);
                f32x16& A = ct ? acc1 : acc0;
                A = __builtin_amdgcn_mfma_f32_32x32x16_bf16(AH, pH.v, A, 0, 0, 0);
                A = __builtin_amdgcn_mfma_f32_32x32x16_bf16(AH, pL.v, A, 0, 0, 0);
                A = __builtin_amdgcn_mfma_f32_32x32x16_bf16(AL, pH.v, A, 0, 0, 0);
            }
        }
    }

    // cross-wave (K-split) reduction over 8 waves
    __shared__ float red[64][33];
    for (int ww = 0; ww < 8; ++ww) {
        if (w == ww) {
            #pragma unroll
            for (int ct = 0; ct < 2; ++ct) {
                const f32x16& A = ct ? acc1 : acc0;
                #pragma unroll
                for (int r = 0; r < 16; ++r) {
                    int c = ct*32 + (r & 3) + 8*(r >> 2) + 4*hi;   // C/D row map
                    if (ww == 0) red[c][l31]  = A[r];
                    else         red[c][l31] += A[r];
                }
            }
        }
        __syncthreads();
    }
    #pragma unroll
    for (int i = 0; i < 4; ++i) {
        int e = t + 512*i;
        int c = e >> 5, m = e & 31;
        size_t gi = (size_t)c*N + m0 + m;
        float xv = __builtin_nontemporal_load(x + gi);
        __builtin_nontemporal_store(gamma * red[c][m] + xv, out + gi);
    }
}

// ---------------------------------------------------------------------------
extern "C" void kernel_launch(void* const* d_in, const int* in_sizes, int n_in,
                              void* d_out, int out_size, void* d_ws, size_t ws_size,
                              hipStream_t stream)
{
    (void)in_sizes; (void)n_in; (void)out_size; (void)ws_size;
    const float* x1  = (const float*)d_in[0];
    const float* x2  = (const float*)d_in[1];
    const float* Wf  = (const float*)d_in[2];
    const float* bf  = (const float*)d_in[3];
    const float* Wg  = (const float*)d_in[4];
    const float* bg  = (const float*)d_in[5];
    const float* Wh1 = (const float*)d_in[6];
    const float* bh1 = (const float*)d_in[7];
    const float* Wh2 = (const float*)d_in[8];
    const float* bh2 = (const float*)d_in[9];
    const float* g1  = (const float*)d_in[10];
    const float* g2  = (const float*)d_in[11];
    float* out = (float*)d_out;
    float* ws  = (float*)d_ws;

    prep_kernel   <<<dim3(N/64, 2), dim3(256), 0, stream>>>(x1,x2,Wf,bf,Wg,bg,Wh1,bh1,Wh2,bh2,ws);
    rownorm_kernel<<<dim3(N/32, 2), dim3(512), 0, stream>>>(ws);
    attn_kernel   <<<dim3(N/32, 2), dim3(512), 0, stream>>>(x1,x2,g1,g2,ws,out);
}

// Round 6
// 185.023 us; speedup vs baseline: 1.5011x; 1.0740x over previous
//
#include <hip/hip_runtime.h>
#include <math.h>

#define N 8192
#define WSP (80*N)          // per-attend workspace floats
#define OFF_G (8*N)         // G bf16 hi/lo [N][16] ushort
#define OFF_T (16*N)        // vb fp32 (prep) -> per-chunk bf16 hi/lo tiles (rownorm)
// F at base: [N][16] ushort = row n: fh[0..7], fl[0..7]  (f pre-scaled by log2e)
// G at OFF_G: same layout for g.
// tiles after rownorm: per 32-row chunk b (4096 ushorts each at OFF_T):
//   ushort tileH[64][32], tileL[64][32]; row c, position q holds vt[n0+sigma(q)][c]
//   with sigma(q) = (q>>4)*16 + (q&3) + 8*((q>>2)&1) + 4*((q>>3)&1)  — the 32x32
//   MFMA C/D row permutation, so exp2(S) packs DIRECTLY into PV B-fragments.

typedef __attribute__((ext_vector_type(8)))  short bf16x8;
typedef __attribute__((ext_vector_type(4)))  float f32x4;
typedef __attribute__((ext_vector_type(16))) float f32x16;

#define ZERO16 ((f32x16){0.f,0.f,0.f,0.f,0.f,0.f,0.f,0.f,0.f,0.f,0.f,0.f,0.f,0.f,0.f,0.f})

#if defined(__has_builtin)
#  if __has_builtin(__builtin_amdgcn_exp2f)
#    define EXP2(x) __builtin_amdgcn_exp2f(x)
#  endif
#endif
#ifndef EXP2
#  define EXP2(x) exp2f(x)
#endif

__device__ __forceinline__ unsigned short bf_hi(float x) {
    union { float f; unsigned u; } v; v.f = x;
    unsigned r = v.u + 0x7fffu + ((v.u >> 16) & 1u);   // round-to-nearest-even
    return (unsigned short)(r >> 16);
}
__device__ __forceinline__ float bf_f(unsigned short h) {
    union { float f; unsigned u; } v; v.u = ((unsigned)h) << 16;
    return v.f;
}
// pack hi16 of two fp32 bit-patterns: (i1 & 0xffff0000) | (i0 >> 16)
__device__ __forceinline__ unsigned pack_hi16(unsigned i1, unsigned i0) {
#if defined(__has_builtin) && __has_builtin(__builtin_amdgcn_perm)
    return __builtin_amdgcn_perm(i1, i0, 0x07060302u);   // v_perm_b32
#else
    return (i1 & 0xffff0000u) | (i0 >> 16);
#endif
}

// XCD-segregation: attend 0 on XCDs 0-3, attend 1 on XCDs 4-7.
__device__ __forceinline__ void xcd_map(int lin, int& a, int& idx) {
    int xcd = lin & 7;
    a   = xcd >> 2;
    idx = (xcd & 3) | ((lin >> 3) << 2);
}

// ---------------------------------------------------------------------------
// Kernel 0: projections. W staged in LDS (the old version issued ~1280 global
// broadcast loads per thread at 1 wave/SIMD). n-tile 32, 512 threads,
// 2 blocks/CU. Accumulation order identical to previous version.
// ---------------------------------------------------------------------------
__global__ __launch_bounds__(512) void prep_kernel(
    const float* __restrict__ x1, const float* __restrict__ x2,
    const float* __restrict__ Wf, const float* __restrict__ bf,
    const float* __restrict__ Wg, const float* __restrict__ bg,
    const float* __restrict__ Wh1, const float* __restrict__ bh1,
    const float* __restrict__ Wh2, const float* __restrict__ bh2,
    float* __restrict__ ws)
{
    int a, bidx;
    xcd_map(blockIdx.x + (int)gridDim.x * blockIdx.y, a, bidx);   // lin 0..511
    const float* x  = a ? x2  : x1;
    const float* Wh = a ? Wh2 : Wh1;
    const float* bh = a ? bh2 : bh1;
    float* base = ws + (size_t)a * WSP;
    unsigned short* F16 = (unsigned short*)base;           // [N][16]
    unsigned short* G16 = (unsigned short*)(base + OFF_G); // [N][16]
    float* vb = base + OFF_T;                              // [N][64] fp32

    __shared__ float xs[64][33];     // x[c][j] for this n-tile
    __shared__ float Wlds[80][64];   // rows: Wf 0-7, Wg 8-15, Wh 16-79
    __shared__ float blds[80];

    const int n0 = bidx * 32;
    const int t  = threadIdx.x;
    for (int i = t; i < 64*32; i += 512) {
        int c = i >> 5, j = i & 31;
        xs[c][j] = x[(size_t)c*N + n0 + j];
    }
    for (int i = t; i < 80*64; i += 512) {
        int o = i >> 6, c = i & 63;
        float v;
        if (o < 8)       v = Wf[o*64 + c];
        else if (o < 16) v = Wg[(o-8)*64 + c];
        else             v = Wh[(o-16)*64 + c];
        Wlds[o][c] = v;
    }
    if (t < 80) blds[t] = (t < 8) ? bf[t] : (t < 16) ? bg[t-8] : bh[t-16];
    __syncthreads();

    const int j  = t & 31;
    const int og = t >> 5;            // 0..15; outputs o = og + 16k, k=0..4
    float s[5];
    #pragma unroll
    for (int k = 0; k < 5; ++k) s[k] = blds[og + 16*k];
    #pragma unroll 8
    for (int c = 0; c < 64; ++c) {
        float xc = xs[c][j];
        #pragma unroll
        for (int k = 0; k < 5; ++k) s[k] += Wlds[og + 16*k][c] * xc;
    }
    const float LOG2E = 1.44269504088896340736f;
    #pragma unroll
    for (int k = 0; k < 5; ++k) {
        int o = og + 16*k;
        if (o < 8) {
            float v = s[k] * LOG2E;
            unsigned short h = bf_hi(v);
            F16[(size_t)(n0+j)*16 + o]     = h;
            F16[(size_t)(n0+j)*16 + 8 + o] = bf_hi(v - bf_f(h));
        } else if (o < 16) {
            float v = s[k];
            unsigned short h = bf_hi(v);
            G16[(size_t)(n0+j)*16 + (o-8)]     = h;
            G16[(size_t)(n0+j)*16 + 8 + (o-8)] = bf_hi(v - bf_f(h));
        } else {
            vb[(size_t)(n0+j)*64 + (o-16)] = s[k];
        }
    }
}

// ---------------------------------------------------------------------------
// Kernel 1: l[n] = sum_m exp2(f[n].g[m]) via 32x32x16 MFMA logits; then
// vt = v/l emitted as bf16 hi/lo tiles with sigma-permuted rows.
// m-loop unrolled x2 with all loads hoisted (2 independent S-chains).
// ---------------------------------------------------------------------------
__global__ __launch_bounds__(512, 4) void rownorm_kernel(float* __restrict__ ws)
{
    int a, bidx;
    xcd_map(blockIdx.x + (int)gridDim.x * blockIdx.y, a, bidx);   // lin 0..511
    float* base = ws + (size_t)a * WSP;
    const unsigned short* F16 = (const unsigned short*)base;
    const unsigned short* G16 = (const unsigned short*)(base + OFF_G);
    float* vb = base + OFF_T;
    const int n0 = bidx * 32;
    const int t  = threadIdx.x;
    const int w = t >> 6, lane = t & 63, l31 = lane & 31, hi = lane >> 5;

    __shared__ float vbs[32][64];   // staged v rows (in-place overwrite safety)
    __shared__ float lsum[8][32];
    __shared__ float linv[32];

    {   // vb read exactly once -> non-temporal
        const f32x4* vp = (const f32x4*)(vb + (size_t)n0*64);
        f32x4 v = __builtin_nontemporal_load(vp + t);
        *(f32x4*)&vbs[t >> 4][(t & 15) * 4] = v;
    }

    // A fragment: rows n0..n0+31, hi half = fl octet (3-term hi/lo packing)
    const bf16x8 A1 = *(const bf16x8*)(F16 + (size_t)(n0 + l31)*16 + hi*8);
    const bf16x8 z8 = {0,0,0,0,0,0,0,0};
    const bf16x8 A2 = hi ? z8 : A1;      // [fh ; 0]

    f32x16 sum = ZERO16;
    for (int ms = w*(N/8); ms < (w+1)*(N/8); ms += 64) {
        const bf16x8 B1a = *(const bf16x8*)(G16 + (size_t)(ms + l31)*16);
        const bf16x8 B2a = *(const bf16x8*)(G16 + (size_t)(ms + l31)*16 + 8);
        const bf16x8 B1b = *(const bf16x8*)(G16 + (size_t)(ms + 32 + l31)*16);
        const bf16x8 B2b = *(const bf16x8*)(G16 + (size_t)(ms + 32 + l31)*16 + 8);
        f32x16 Sa = __builtin_amdgcn_mfma_f32_32x32x16_bf16(A1, B1a, ZERO16, 0, 0, 0);
        Sa = __builtin_amdgcn_mfma_f32_32x32x16_bf16(A2, B2a, Sa, 0, 0, 0);
        f32x16 Sb = __builtin_amdgcn_mfma_f32_32x32x16_bf16(A1, B1b, ZERO16, 0, 0, 0);
        Sb = __builtin_amdgcn_mfma_f32_32x32x16_bf16(A2, B2b, Sb, 0, 0, 0);
        #pragma unroll
        for (int r = 0; r < 16; ++r) sum[r] += EXP2(Sa[r]) + EXP2(Sb[r]);
    }
    // reduce over the 32 m-columns (within each hi half)
    #pragma unroll
    for (int r = 0; r < 16; ++r) {
        float v = sum[r];
        v += __shfl_xor(v, 1, 64);
        v += __shfl_xor(v, 2, 64);
        v += __shfl_xor(v, 4, 64);
        v += __shfl_xor(v, 8, 64);
        v += __shfl_xor(v, 16, 64);
        sum[r] = v;
    }
    if (l31 == 0) {
        #pragma unroll
        for (int r = 0; r < 16; ++r) {
            int n = (r & 3) + 8*(r >> 2) + 4*hi;
            lsum[w][n] = sum[r];
        }
    }
    __syncthreads();
    if (t < 32) {
        float v = 0.f;
        #pragma unroll
        for (int ww = 0; ww < 8; ++ww) v += lsum[ww][t];
        linv[t] = 1.0f / v;
    }
    __syncthreads();

    // emit tiles: position kk holds vt[n0 + sigma(kk)][c]
    if (t < 256) {
        const int c = t & 63, kkg = t >> 6;
        bf16x8 H, L;
        #pragma unroll
        for (int jj = 0; jj < 8; ++jj) {
            int n_rd = (kkg >> 1)*16 + 4*(kkg & 1) + (jj & 3) + 8*((jj >> 2) & 1);
            float v = vbs[n_rd][c] * linv[n_rd];
            unsigned short h = bf_hi(v);
            H[jj] = (short)h;
            L[jj] = (short)bf_hi(v - bf_f(h));
        }
        unsigned short* tile = (unsigned short*)(base + OFF_T) + (size_t)(n0 >> 5) * 4096;
        unsigned short* tp = tile + c*32 + kkg*8;
        *(bf16x8*)tp          = H;
        *(bf16x8*)(tp + 2048) = L;
    }
}

// ---------------------------------------------------------------------------
// Kernel 2: sa[c][m] = sum_n vt[n][c] * exp2(f[n].g[m]).
// Software-pipelined: A-fragment loaded 2 iters ahead, PV tiles prefetched
// 1 iter ahead (issued after last use); pack via v_perm_b32.
// ---------------------------------------------------------------------------
__global__ __launch_bounds__(512, 4) void attn_kernel(
    const float* __restrict__ x1, const float* __restrict__ x2,
    const float* __restrict__ ga1, const float* __restrict__ ga2,
    const float* __restrict__ ws, float* __restrict__ out_)
{
    int a, bidx;
    xcd_map(blockIdx.x + (int)gridDim.x * blockIdx.y, a, bidx);   // lin 0..511
    const float* x = a ? x2 : x1;
    const float gamma = a ? ga2[0] : ga1[0];
    const float* base = ws + (size_t)a * WSP;
    const unsigned short* F16 = (const unsigned short*)base;
    const unsigned short* G16 = (const unsigned short*)(base + OFF_G);
    const unsigned short* tiles = (const unsigned short*)(base + OFF_T);
    float* out = out_ + (size_t)a * ((size_t)64 * N);

    const int m0 = bidx * 32;
    const int t = threadIdx.x;
    const int w = t >> 6, lane = t & 63, l31 = lane & 31, hi = lane >> 5;

    // g fragments for the block's 32 m-columns (resident all kernel)
    const bf16x8 Bh = *(const bf16x8*)(G16 + (size_t)(m0 + l31)*16);          // [gh;gh]
    const bf16x8 Bl_raw = *(const bf16x8*)(G16 + (size_t)(m0 + l31)*16 + 8);
    const bf16x8 z8 = {0,0,0,0,0,0,0,0};
    const bf16x8 Bl = hi ? z8 : Bl_raw;                                        // [gl;0]

    f32x16 acc0 = ZERO16, acc1 = ZERO16;

    const int kbeg = w * (N/8);
    const int KM = (N/8) - 1;      // wrap mask within this wave's K-range

    f32x16 S;
    bf16x8 Acur, Anxt;
    bf16x8 AH[4], AL[4];           // PV tiles for the CURRENT iteration

    // prologue: A for it=0 and it=1; tiles for it=0
    Acur = *(const bf16x8*)(F16 + (size_t)(kbeg + l31)*16 + hi*8);
    Anxt = *(const bf16x8*)(F16 + (size_t)(kbeg + 32 + l31)*16 + hi*8);
    {
        const unsigned short* tb = tiles + (size_t)(kbeg >> 5) * 4096;
        #pragma unroll
        for (int kp = 0; kp < 2; ++kp)
            #pragma unroll
            for (int ct = 0; ct < 2; ++ct) {
                const unsigned short* tc = tb + (ct*32 + l31)*32 + kp*16 + hi*8;
                AH[kp*2+ct] = *(const bf16x8*)tc;
                AL[kp*2+ct] = *(const bf16x8*)(tc + 2048);
            }
    }

    for (int it = 0; it < 32; ++it) {
        // logits for current step (Acur loaded >=1 iter ago)
        S = __builtin_amdgcn_mfma_f32_32x32x16_bf16(Acur, Bh, ZERO16, 0, 0, 0);
        S = __builtin_amdgcn_mfma_f32_32x32x16_bf16(Acur, Bl, S, 0, 0, 0);
        Acur = Anxt;
        // issue A-load for it+2 (wraps harmlessly at the end)
        Anxt = *(const bf16x8*)(F16 + (size_t)(kbeg + (((it+2)*32) & KM) + l31)*16 + hi*8);

        // pack p = exp2(S) into PV B-fragments (hi + truncation residual)
        union BU { bf16x8 v; unsigned u[4]; } pH[2], pL[2];
        #pragma unroll
        for (int kp = 0; kp < 2; ++kp)
            #pragma unroll
            for (int d = 0; d < 4; ++d) {
                float p0 = EXP2(S[kp*8 + 2*d]);
                float p1 = EXP2(S[kp*8 + 2*d + 1]);
                unsigned i0 = __float_as_uint(p0), i1 = __float_as_uint(p1);
                pH[kp].u[d] = pack_hi16(i1, i0);
                unsigned r0 = __float_as_uint(p0 - __uint_as_float(i0 & 0xffff0000u));
                unsigned r1 = __float_as_uint(p1 - __uint_as_float(i1 & 0xffff0000u));
                pL[kp].u[d] = pack_hi16(r1, r0);
            }

        // PV MFMAs with current tiles
        #pragma unroll
        for (int kp = 0; kp < 2; ++kp) {
            acc0 = __builtin_amdgcn_mfma_f32_32x32x16_bf16(AH[kp*2+0], pH[kp].v, acc0, 0, 0, 0);
            acc0 = __builtin_amdgcn_mfma_f32_32x32x16_bf16(AH[kp*2+0], pL[kp].v, acc0, 0, 0, 0);
            acc0 = __builtin_amdgcn_mfma_f32_32x32x16_bf16(AL[kp*2+0], pH[kp].v, acc0, 0, 0, 0);
            acc1 = __builtin_amdgcn_mfma_f32_32x32x16_bf16(AH[kp*2+1], pH[kp].v, acc1, 0, 0, 0);
            acc1 = __builtin_amdgcn_mfma_f32_32x32x16_bf16(AH[kp*2+1], pL[kp].v, acc1, 0, 0, 0);
            acc1 = __builtin_amdgcn_mfma_f32_32x32x16_bf16(AL[kp*2+1], pH[kp].v, acc1, 0, 0, 0);
        }

        // prefetch tiles for next iteration (issued after last use of AH/AL)
        {
            const unsigned short* tb = tiles
                + (size_t)((kbeg + (((it+1)*32) & KM)) >> 5) * 4096;
            #pragma unroll
            for (int kp = 0; kp < 2; ++kp)
                #pragma unroll
                for (int ct = 0; ct < 2; ++ct) {
                    const unsigned short* tc = tb + (ct*32 + l31)*32 + kp*16 + hi*8;
                    AH[kp*2+ct] = *(const bf16x8*)tc;
                    AL[kp*2+ct] = *(const bf16x8*)(tc + 2048);
                }
        }
    }

    // cross-wave (K-split) reduction over 8 waves
    __shared__ float red[64][33];
    for (int ww = 0; ww < 8; ++ww) {
        if (w == ww) {
            #pragma unroll
            for (int ct = 0; ct < 2; ++ct) {
                const f32x16& A = ct ? acc1 : acc0;
                #pragma unroll
                for (int r = 0; r < 16; ++r) {
                    int c = ct*32 + (r & 3) + 8*(r >> 2) + 4*hi;   // C/D row map
                    if (ww == 0) red[c][l31]  = A[r];
                    else         red[c][l31] += A[r];
                }
            }
        }
        __syncthreads();
    }
    #pragma unroll
    for (int i = 0; i < 4; ++i) {
        int e = t + 512*i;
        int c = e >> 5, m = e & 31;
        size_t gi = (size_t)c*N + m0 + m;
        float xv = __builtin_nontemporal_load(x + gi);
        __builtin_nontemporal_store(gamma * red[c][m] + xv, out + gi);
    }
}

// ---------------------------------------------------------------------------
extern "C" void kernel_launch(void* const* d_in, const int* in_sizes, int n_in,
                              void* d_out, int out_size, void* d_ws, size_t ws_size,
                              hipStream_t stream)
{
    (void)in_sizes; (void)n_in; (void)out_size; (void)ws_size;
    const float* x1  = (const float*)d_in[0];
    const float* x2  = (const float*)d_in[1];
    const float* Wf  = (const float*)d_in[2];
    const float* bf  = (const float*)d_in[3];
    const float* Wg  = (const float*)d_in[4];
    const float* bg  = (const float*)d_in[5];
    const float* Wh1 = (const float*)d_in[6];
    const float* bh1 = (const float*)d_in[7];
    const float* Wh2 = (const float*)d_in[8];
    const float* bh2 = (const float*)d_in[9];
    const float* g1  = (const float*)d_in[10];
    const float* g2  = (const float*)d_in[11];
    float* out = (float*)d_out;
    float* ws  = (float*)d_ws;

    prep_kernel   <<<dim3(N/32, 2), dim3(512), 0, stream>>>(x1,x2,Wf,bf,Wg,bg,Wh1,bh1,Wh2,bh2,ws);
    rownorm_kernel<<<dim3(N/32, 2), dim3(512), 0, stream>>>(ws);
    attn_kernel   <<<dim3(N/32, 2), dim3(512), 0, stream>>>(x1,x2,g1,g2,ws,out);
}

// Round 7
// 170.263 us; speedup vs baseline: 1.6312x; 1.0867x over previous
//
#include <hip/hip_runtime.h>
#include <math.h>

#define N 8192
#define WSP (80*N)          // per-attend workspace floats
#define OFF_G (8*N)         // G bf16 hi/lo [N][16] ushort
#define OFF_T (16*N)        // vb fp32 (prep) -> per-chunk bf16 hi/lo tiles (rownorm)
// F at base: [N][16] ushort = row n: fh[0..7], fl[0..7]  (f pre-scaled by log2e)
// G at OFF_G: same layout for g.
// tiles after rownorm: per 32-row chunk b (4096 ushorts each at OFF_T):
//   ushort tileH[64][32], tileL[64][32]; row c, position q holds vt[n0+sigma(q)][c]
//   with sigma(q) the 32x32 MFMA C/D row permutation, so exp2(S) packs DIRECTLY
//   into PV B-fragments.

typedef __attribute__((ext_vector_type(8)))  short bf16x8;
typedef __attribute__((ext_vector_type(4)))  float f32x4;
typedef __attribute__((ext_vector_type(16))) float f32x16;

#define ZERO16 ((f32x16){0.f,0.f,0.f,0.f,0.f,0.f,0.f,0.f,0.f,0.f,0.f,0.f,0.f,0.f,0.f,0.f})

#if defined(__has_builtin)
#  if __has_builtin(__builtin_amdgcn_exp2f)
#    define EXP2(x) __builtin_amdgcn_exp2f(x)
#  endif
#endif
#ifndef EXP2
#  define EXP2(x) exp2f(x)
#endif

__device__ __forceinline__ unsigned short bf_hi(float x) {
    union { float f; unsigned u; } v; v.f = x;
    unsigned r = v.u + 0x7fffu + ((v.u >> 16) & 1u);   // round-to-nearest-even
    return (unsigned short)(r >> 16);
}
__device__ __forceinline__ float bf_f(unsigned short h) {
    union { float f; unsigned u; } v; v.u = ((unsigned)h) << 16;
    return v.f;
}
// pack hi16 of two fp32 bit-patterns: (i1 & 0xffff0000) | (i0 >> 16)
__device__ __forceinline__ unsigned pack_hi16(unsigned i1, unsigned i0) {
#if defined(__has_builtin) && __has_builtin(__builtin_amdgcn_perm)
    return __builtin_amdgcn_perm(i1, i0, 0x07060302u);   // v_perm_b32
#else
    return (i1 & 0xffff0000u) | (i0 >> 16);
#endif
}

// XCD-segregation: attend 0 on XCDs 0-3, attend 1 on XCDs 4-7.
__device__ __forceinline__ void xcd_map(int lin, int& a, int& idx) {
    int xcd = lin & 7;
    a   = xcd >> 2;
    idx = (xcd & 3) | ((lin >> 3) << 2);
}

// ---------------------------------------------------------------------------
// Kernel 0: projections (W staged in LDS). Unchanged from round 6.
// ---------------------------------------------------------------------------
__global__ __launch_bounds__(512) void prep_kernel(
    const float* __restrict__ x1, const float* __restrict__ x2,
    const float* __restrict__ Wf, const float* __restrict__ bf,
    const float* __restrict__ Wg, const float* __restrict__ bg,
    const float* __restrict__ Wh1, const float* __restrict__ bh1,
    const float* __restrict__ Wh2, const float* __restrict__ bh2,
    float* __restrict__ ws)
{
    int a, bidx;
    xcd_map(blockIdx.x + (int)gridDim.x * blockIdx.y, a, bidx);   // lin 0..511
    const float* x  = a ? x2  : x1;
    const float* Wh = a ? Wh2 : Wh1;
    const float* bh = a ? bh2 : bh1;
    float* base = ws + (size_t)a * WSP;
    unsigned short* F16 = (unsigned short*)base;           // [N][16]
    unsigned short* G16 = (unsigned short*)(base + OFF_G); // [N][16]
    float* vb = base + OFF_T;                              // [N][64] fp32

    __shared__ float xs[64][33];     // x[c][j] for this n-tile
    __shared__ float Wlds[80][64];   // rows: Wf 0-7, Wg 8-15, Wh 16-79
    __shared__ float blds[80];

    const int n0 = bidx * 32;
    const int t  = threadIdx.x;
    for (int i = t; i < 64*32; i += 512) {
        int c = i >> 5, j = i & 31;
        xs[c][j] = x[(size_t)c*N + n0 + j];
    }
    for (int i = t; i < 80*64; i += 512) {
        int o = i >> 6, c = i & 63;
        float v;
        if (o < 8)       v = Wf[o*64 + c];
        else if (o < 16) v = Wg[(o-8)*64 + c];
        else             v = Wh[(o-16)*64 + c];
        Wlds[o][c] = v;
    }
    if (t < 80) blds[t] = (t < 8) ? bf[t] : (t < 16) ? bg[t-8] : bh[t-16];
    __syncthreads();

    const int j  = t & 31;
    const int og = t >> 5;            // 0..15; outputs o = og + 16k, k=0..4
    float s[5];
    #pragma unroll
    for (int k = 0; k < 5; ++k) s[k] = blds[og + 16*k];
    #pragma unroll 8
    for (int c = 0; c < 64; ++c) {
        float xc = xs[c][j];
        #pragma unroll
        for (int k = 0; k < 5; ++k) s[k] += Wlds[og + 16*k][c] * xc;
    }
    const float LOG2E = 1.44269504088896340736f;
    #pragma unroll
    for (int k = 0; k < 5; ++k) {
        int o = og + 16*k;
        if (o < 8) {
            float v = s[k] * LOG2E;
            unsigned short h = bf_hi(v);
            F16[(size_t)(n0+j)*16 + o]     = h;
            F16[(size_t)(n0+j)*16 + 8 + o] = bf_hi(v - bf_f(h));
        } else if (o < 16) {
            float v = s[k];
            unsigned short h = bf_hi(v);
            G16[(size_t)(n0+j)*16 + (o-8)]     = h;
            G16[(size_t)(n0+j)*16 + 8 + (o-8)] = bf_hi(v - bf_f(h));
        } else {
            vb[(size_t)(n0+j)*64 + (o-16)] = s[k];
        }
    }
}

// ---------------------------------------------------------------------------
// Kernel 1: softmax denominators via MFMA logits + tile emit. Unchanged.
// ---------------------------------------------------------------------------
__global__ __launch_bounds__(512, 4) void rownorm_kernel(float* __restrict__ ws)
{
    int a, bidx;
    xcd_map(blockIdx.x + (int)gridDim.x * blockIdx.y, a, bidx);   // lin 0..511
    float* base = ws + (size_t)a * WSP;
    const unsigned short* F16 = (const unsigned short*)base;
    const unsigned short* G16 = (const unsigned short*)(base + OFF_G);
    float* vb = base + OFF_T;
    const int n0 = bidx * 32;
    const int t  = threadIdx.x;
    const int w = t >> 6, lane = t & 63, l31 = lane & 31, hi = lane >> 5;

    __shared__ float vbs[32][64];   // staged v rows (in-place overwrite safety)
    __shared__ float lsum[8][32];
    __shared__ float linv[32];

    {   // vb read exactly once -> non-temporal
        const f32x4* vp = (const f32x4*)(vb + (size_t)n0*64);
        f32x4 v = __builtin_nontemporal_load(vp + t);
        *(f32x4*)&vbs[t >> 4][(t & 15) * 4] = v;
    }

    // A fragment: rows n0..n0+31, hi half = fl octet (3-term hi/lo packing)
    const bf16x8 A1 = *(const bf16x8*)(F16 + (size_t)(n0 + l31)*16 + hi*8);
    const bf16x8 z8 = {0,0,0,0,0,0,0,0};
    const bf16x8 A2 = hi ? z8 : A1;      // [fh ; 0]

    f32x16 sum = ZERO16;
    for (int ms = w*(N/8); ms < (w+1)*(N/8); ms += 64) {
        const bf16x8 B1a = *(const bf16x8*)(G16 + (size_t)(ms + l31)*16);
        const bf16x8 B2a = *(const bf16x8*)(G16 + (size_t)(ms + l31)*16 + 8);
        const bf16x8 B1b = *(const bf16x8*)(G16 + (size_t)(ms + 32 + l31)*16);
        const bf16x8 B2b = *(const bf16x8*)(G16 + (size_t)(ms + 32 + l31)*16 + 8);
        f32x16 Sa = __builtin_amdgcn_mfma_f32_32x32x16_bf16(A1, B1a, ZERO16, 0, 0, 0);
        Sa = __builtin_amdgcn_mfma_f32_32x32x16_bf16(A2, B2a, Sa, 0, 0, 0);
        f32x16 Sb = __builtin_amdgcn_mfma_f32_32x32x16_bf16(A1, B1b, ZERO16, 0, 0, 0);
        Sb = __builtin_amdgcn_mfma_f32_32x32x16_bf16(A2, B2b, Sb, 0, 0, 0);
        #pragma unroll
        for (int r = 0; r < 16; ++r) sum[r] += EXP2(Sa[r]) + EXP2(Sb[r]);
    }
    #pragma unroll
    for (int r = 0; r < 16; ++r) {
        float v = sum[r];
        v += __shfl_xor(v, 1, 64);
        v += __shfl_xor(v, 2, 64);
        v += __shfl_xor(v, 4, 64);
        v += __shfl_xor(v, 8, 64);
        v += __shfl_xor(v, 16, 64);
        sum[r] = v;
    }
    if (l31 == 0) {
        #pragma unroll
        for (int r = 0; r < 16; ++r) {
            int n = (r & 3) + 8*(r >> 2) + 4*hi;
            lsum[w][n] = sum[r];
        }
    }
    __syncthreads();
    if (t < 32) {
        float v = 0.f;
        #pragma unroll
        for (int ww = 0; ww < 8; ++ww) v += lsum[ww][t];
        linv[t] = 1.0f / v;
    }
    __syncthreads();

    // emit tiles: position kk holds vt[n0 + sigma(kk)][c]
    if (t < 256) {
        const int c = t & 63, kkg = t >> 6;
        bf16x8 H, L;
        #pragma unroll
        for (int jj = 0; jj < 8; ++jj) {
            int n_rd = (kkg >> 1)*16 + 4*(kkg & 1) + (jj & 3) + 8*((jj >> 2) & 1);
            float v = vbs[n_rd][c] * linv[n_rd];
            unsigned short h = bf_hi(v);
            H[jj] = (short)h;
            L[jj] = (short)bf_hi(v - bf_f(h));
        }
        unsigned short* tile = (unsigned short*)(base + OFF_T) + (size_t)(n0 >> 5) * 4096;
        unsigned short* tp = tile + c*32 + kkg*8;
        *(bf16x8*)tp          = H;
        *(bf16x8*)(tp + 2048) = L;
    }
}

// ---------------------------------------------------------------------------
// Kernel 2: sa[c][m] = sum_n vt[n][c] * exp2(f[n].g[m]).
// m-tile 64 PER WAVE: two independent logit->exp2->PV chains share one A-frag
// and one tile-read stream (tile traffic halves; ILP doubles so one chain's
// MFMA/exp2 latency hides under the other). launch_bounds(512,2) raises the
// VGPR cap to 256 so the 2-iter A / 1-iter tile prefetch actually stays in
// registers (round 6 was compiled to 64 VGPR -> prefetch was serialized).
// ---------------------------------------------------------------------------
__global__ __launch_bounds__(512, 2) void attn_kernel(
    const float* __restrict__ x1, const float* __restrict__ x2,
    const float* __restrict__ ga1, const float* __restrict__ ga2,
    const float* __restrict__ ws, float* __restrict__ out_)
{
    int a, bidx;
    xcd_map(blockIdx.x + (int)gridDim.x * blockIdx.y, a, bidx);   // lin 0..255
    const float* x = a ? x2 : x1;
    const float gamma = a ? ga2[0] : ga1[0];
    const float* base = ws + (size_t)a * WSP;
    const unsigned short* F16 = (const unsigned short*)base;
    const unsigned short* G16 = (const unsigned short*)(base + OFF_G);
    const unsigned short* tiles = (const unsigned short*)(base + OFF_T);
    float* out = out_ + (size_t)a * ((size_t)64 * N);

    const int m0 = bidx * 64;
    const int t = threadIdx.x;
    const int w = t >> 6, lane = t & 63, l31 = lane & 31, hi = lane >> 5;

    // g fragments for the wave's TWO 32-col m-groups (resident all kernel)
    const bf16x8 z8 = {0,0,0,0,0,0,0,0};
    bf16x8 Bh0, Bl0, Bh1, Bl1;
    {
        const unsigned short* gp0 = G16 + (size_t)(m0 + l31)*16;
        const unsigned short* gp1 = G16 + (size_t)(m0 + 32 + l31)*16;
        Bh0 = *(const bf16x8*)gp0;
        Bl0 = hi ? z8 : *(const bf16x8*)(gp0 + 8);
        Bh1 = *(const bf16x8*)gp1;
        Bl1 = hi ? z8 : *(const bf16x8*)(gp1 + 8);
    }

    f32x16 accA = ZERO16, accB = ZERO16;   // mg0: ct=0, ct=1
    f32x16 accC = ZERO16, accD = ZERO16;   // mg1: ct=0, ct=1

    const int kbeg = w * (N/8);
    const int KM = (N/8) - 1;      // wrap mask within this wave's K-range

    bf16x8 Acur, Anxt;
    bf16x8 AH[4], AL[4];           // PV tiles for the CURRENT iteration

    // prologue: A for it=0 and it=1; tiles for it=0
    Acur = *(const bf16x8*)(F16 + (size_t)(kbeg + l31)*16 + hi*8);
    Anxt = *(const bf16x8*)(F16 + (size_t)(kbeg + 32 + l31)*16 + hi*8);
    {
        const unsigned short* tb = tiles + (size_t)(kbeg >> 5) * 4096;
        #pragma unroll
        for (int kp = 0; kp < 2; ++kp)
            #pragma unroll
            for (int ct = 0; ct < 2; ++ct) {
                const unsigned short* tc = tb + (ct*32 + l31)*32 + kp*16 + hi*8;
                AH[kp*2+ct] = *(const bf16x8*)tc;
                AL[kp*2+ct] = *(const bf16x8*)(tc + 2048);
            }
    }

    for (int it = 0; it < 32; ++it) {
        // logits for both m-groups (independent chains off the shared A-frag)
        f32x16 S0 = __builtin_amdgcn_mfma_f32_32x32x16_bf16(Acur, Bh0, ZERO16, 0, 0, 0);
        f32x16 S1 = __builtin_amdgcn_mfma_f32_32x32x16_bf16(Acur, Bh1, ZERO16, 0, 0, 0);
        S0 = __builtin_amdgcn_mfma_f32_32x32x16_bf16(Acur, Bl0, S0, 0, 0, 0);
        S1 = __builtin_amdgcn_mfma_f32_32x32x16_bf16(Acur, Bl1, S1, 0, 0, 0);
        Acur = Anxt;
        // issue A-load for it+2 (wraps harmlessly at the end)
        Anxt = *(const bf16x8*)(F16 + (size_t)(kbeg + (((it+2)*32) & KM) + l31)*16 + hi*8);

        // pack p = exp2(S) into PV B-fragments (hi + truncation residual)
        union BU { bf16x8 v; unsigned u[4]; };
        BU pH0[2], pL0[2], pH1[2], pL1[2];
        #pragma unroll
        for (int kp = 0; kp < 2; ++kp)
            #pragma unroll
            for (int d = 0; d < 4; ++d) {
                float q0 = EXP2(S0[kp*8 + 2*d]);
                float q1 = EXP2(S0[kp*8 + 2*d + 1]);
                unsigned i0 = __float_as_uint(q0), i1 = __float_as_uint(q1);
                pH0[kp].u[d] = pack_hi16(i1, i0);
                unsigned r0 = __float_as_uint(q0 - __uint_as_float(i0 & 0xffff0000u));
                unsigned r1 = __float_as_uint(q1 - __uint_as_float(i1 & 0xffff0000u));
                pL0[kp].u[d] = pack_hi16(r1, r0);

                float q2 = EXP2(S1[kp*8 + 2*d]);
                float q3 = EXP2(S1[kp*8 + 2*d + 1]);
                unsigned i2 = __float_as_uint(q2), i3 = __float_as_uint(q3);
                pH1[kp].u[d] = pack_hi16(i3, i2);
                unsigned r2 = __float_as_uint(q2 - __uint_as_float(i2 & 0xffff0000u));
                unsigned r3 = __float_as_uint(q3 - __uint_as_float(i3 & 0xffff0000u));
                pL1[kp].u[d] = pack_hi16(r3, r2);
            }

        // PV MFMAs: both chains consume the same tiles
        #pragma unroll
        for (int kp = 0; kp < 2; ++kp) {
            accA = __builtin_amdgcn_mfma_f32_32x32x16_bf16(AH[kp*2+0], pH0[kp].v, accA, 0, 0, 0);
            accC = __builtin_amdgcn_mfma_f32_32x32x16_bf16(AH[kp*2+0], pH1[kp].v, accC, 0, 0, 0);
            accA = __builtin_amdgcn_mfma_f32_32x32x16_bf16(AH[kp*2+0], pL0[kp].v, accA, 0, 0, 0);
            accC = __builtin_amdgcn_mfma_f32_32x32x16_bf16(AH[kp*2+0], pL1[kp].v, accC, 0, 0, 0);
            accA = __builtin_amdgcn_mfma_f32_32x32x16_bf16(AL[kp*2+0], pH0[kp].v, accA, 0, 0, 0);
            accC = __builtin_amdgcn_mfma_f32_32x32x16_bf16(AL[kp*2+0], pH1[kp].v, accC, 0, 0, 0);
            accB = __builtin_amdgcn_mfma_f32_32x32x16_bf16(AH[kp*2+1], pH0[kp].v, accB, 0, 0, 0);
            accD = __builtin_amdgcn_mfma_f32_32x32x16_bf16(AH[kp*2+1], pH1[kp].v, accD, 0, 0, 0);
            accB = __builtin_amdgcn_mfma_f32_32x32x16_bf16(AH[kp*2+1], pL0[kp].v, accB, 0, 0, 0);
            accD = __builtin_amdgcn_mfma_f32_32x32x16_bf16(AH[kp*2+1], pL1[kp].v, accD, 0, 0, 0);
            accB = __builtin_amdgcn_mfma_f32_32x32x16_bf16(AL[kp*2+1], pH0[kp].v, accB, 0, 0, 0);
            accD = __builtin_amdgcn_mfma_f32_32x32x16_bf16(AL[kp*2+1], pH1[kp].v, accD, 0, 0, 0);
        }

        // prefetch tiles for next iteration (issued after last use of AH/AL)
        {
            const unsigned short* tb = tiles
                + (size_t)((kbeg + (((it+1)*32) & KM)) >> 5) * 4096;
            #pragma unroll
            for (int kp = 0; kp < 2; ++kp)
                #pragma unroll
                for (int ct = 0; ct < 2; ++ct) {
                    const unsigned short* tc = tb + (ct*32 + l31)*32 + kp*16 + hi*8;
                    AH[kp*2+ct] = *(const bf16x8*)tc;
                    AL[kp*2+ct] = *(const bf16x8*)(tc + 2048);
                }
        }
    }

    // cross-wave (K-split) reduction over 8 waves; 64c x 64m block tile
    __shared__ float red[64][65];
    for (int ww = 0; ww < 8; ++ww) {
        if (w == ww) {
            #pragma unroll
            for (int mg = 0; mg < 2; ++mg)
                #pragma unroll
                for (int ct = 0; ct < 2; ++ct) {
                    const f32x16& A = mg ? (ct ? accD : accC) : (ct ? accB : accA);
                    #pragma unroll
                    for (int r = 0; r < 16; ++r) {
                        int c = ct*32 + (r & 3) + 8*(r >> 2) + 4*hi;   // C/D row map
                        int m = mg*32 + l31;
                        if (ww == 0) red[c][m]  = A[r];
                        else         red[c][m] += A[r];
                    }
                }
        }
        __syncthreads();
    }
    #pragma unroll
    for (int i = 0; i < 8; ++i) {
        int e = t + 512*i;
        int c = e >> 6, m = e & 63;
        size_t gi = (size_t)c*N + m0 + m;
        float xv = __builtin_nontemporal_load(x + gi);
        __builtin_nontemporal_store(gamma * red[c][m] + xv, out + gi);
    }
}

// ---------------------------------------------------------------------------
extern "C" void kernel_launch(void* const* d_in, const int* in_sizes, int n_in,
                              void* d_out, int out_size, void* d_ws, size_t ws_size,
                              hipStream_t stream)
{
    (void)in_sizes; (void)n_in; (void)out_size; (void)ws_size;
    const float* x1  = (const float*)d_in[0];
    const float* x2  = (const float*)d_in[1];
    const float* Wf  = (const float*)d_in[2];
    const float* bf  = (const float*)d_in[3];
    const float* Wg  = (const float*)d_in[4];
    const float* bg  = (const float*)d_in[5];
    const float* Wh1 = (const float*)d_in[6];
    const float* bh1 = (const float*)d_in[7];
    const float* Wh2 = (const float*)d_in[8];
    const float* bh2 = (const float*)d_in[9];
    const float* g1  = (const float*)d_in[10];
    const float* g2  = (const float*)d_in[11];
    float* out = (float*)d_out;
    float* ws  = (float*)d_ws;

    prep_kernel   <<<dim3(N/32, 2), dim3(512), 0, stream>>>(x1,x2,Wf,bf,Wg,bg,Wh1,bh1,Wh2,bh2,ws);
    rownorm_kernel<<<dim3(N/32, 2), dim3(512), 0, stream>>>(ws);
    attn_kernel   <<<dim3(N/64, 2), dim3(512), 0, stream>>>(x1,x2,g1,g2,ws,out);
}

// Round 8
// 168.313 us; speedup vs baseline: 1.6501x; 1.0116x over previous
//
#include <hip/hip_runtime.h>
#include <math.h>

#define N 8192
#define WSP (80*N)          // per-attend workspace floats
#define OFF_G (8*N)         // G bf16 hi/lo [N][16] ushort
#define OFF_T (16*N)        // vb fp32 (prep) -> per-chunk bf16 hi/lo tiles (rownorm)
// F at base: [N][16] ushort = row n: fh[0..7], fl[0..7]  (f pre-scaled by log2e)
// G at OFF_G: same layout for g.
// tiles after rownorm: per 32-row chunk b (4096 ushorts each at OFF_T):
//   ushort tileH[64][32], tileL[64][32]; row c, position q holds vt[n0+sigma(q)][c]
//   with sigma(q) the 32x32 MFMA C/D row permutation, so exp2(S) packs DIRECTLY
//   into PV B-fragments.

typedef __attribute__((ext_vector_type(8)))  short bf16x8;
typedef __attribute__((ext_vector_type(4)))  float f32x4;
typedef __attribute__((ext_vector_type(16))) float f32x16;

#define ZERO16 ((f32x16){0.f,0.f,0.f,0.f,0.f,0.f,0.f,0.f,0.f,0.f,0.f,0.f,0.f,0.f,0.f,0.f})

#if defined(__has_builtin)
#  if __has_builtin(__builtin_amdgcn_exp2f)
#    define EXP2(x) __builtin_amdgcn_exp2f(x)
#  endif
#endif
#ifndef EXP2
#  define EXP2(x) exp2f(x)
#endif

__device__ __forceinline__ unsigned short bf_hi(float x) {
    union { float f; unsigned u; } v; v.f = x;
    unsigned r = v.u + 0x7fffu + ((v.u >> 16) & 1u);   // round-to-nearest-even
    return (unsigned short)(r >> 16);
}
__device__ __forceinline__ float bf_f(unsigned short h) {
    union { float f; unsigned u; } v; v.u = ((unsigned)h) << 16;
    return v.f;
}
// pack hi16 of two fp32 bit-patterns: (i1 & 0xffff0000) | (i0 >> 16)
__device__ __forceinline__ unsigned pack_hi16(unsigned i1, unsigned i0) {
#if defined(__has_builtin) && __has_builtin(__builtin_amdgcn_perm)
    return __builtin_amdgcn_perm(i1, i0, 0x07060302u);   // v_perm_b32
#else
    return (i1 & 0xffff0000u) | (i0 >> 16);
#endif
}

// XCD-segregation: attend 0 on XCDs 0-3, attend 1 on XCDs 4-7.
__device__ __forceinline__ void xcd_map(int lin, int& a, int& idx) {
    int xcd = lin & 7;
    a   = xcd >> 2;
    idx = (xcd & 3) | ((lin >> 3) << 2);
}

// ---------------------------------------------------------------------------
// Kernel 0: projections (W staged in LDS, float4 LDS reads).
// Accumulation order element-identical to round 6/7 (bit-identical outputs).
// ---------------------------------------------------------------------------
__global__ __launch_bounds__(512) void prep_kernel(
    const float* __restrict__ x1, const float* __restrict__ x2,
    const float* __restrict__ Wf, const float* __restrict__ bf,
    const float* __restrict__ Wg, const float* __restrict__ bg,
    const float* __restrict__ Wh1, const float* __restrict__ bh1,
    const float* __restrict__ Wh2, const float* __restrict__ bh2,
    float* __restrict__ ws)
{
    int a, bidx;
    xcd_map(blockIdx.x + (int)gridDim.x * blockIdx.y, a, bidx);   // lin 0..511
    const float* x  = a ? x2  : x1;
    const float* Wh = a ? Wh2 : Wh1;
    const float* bh = a ? bh2 : bh1;
    float* base = ws + (size_t)a * WSP;
    unsigned short* F16 = (unsigned short*)base;           // [N][16]
    unsigned short* G16 = (unsigned short*)(base + OFF_G); // [N][16]
    float* vb = base + OFF_T;                              // [N][64] fp32

    __shared__ __align__(16) float xs[32][68];    // x transposed: xs[j][c]
    __shared__ __align__(16) float Wlds[80][64];  // rows: Wf 0-7, Wg 8-15, Wh 16-79
    __shared__ float blds[80];

    const int n0 = bidx * 32;
    const int t  = threadIdx.x;
    for (int i = t; i < 64*32; i += 512) {
        int c = i >> 5, j = i & 31;
        xs[j][c] = x[(size_t)c*N + n0 + j];
    }
    // W staged as float4 (rows are 256B-aligned in source)
    for (int i4 = t; i4 < 80*16; i4 += 512) {
        int o = i4 >> 4, c4 = i4 & 15;
        const float* src = (o < 8) ? (Wf + o*64) : (o < 16) ? (Wg + (o-8)*64) : (Wh + (o-16)*64);
        *(f32x4*)&Wlds[o][c4*4] = *(const f32x4*)(src + c4*4);
    }
    if (t < 80) blds[t] = (t < 8) ? bf[t] : (t < 16) ? bg[t-8] : bh[t-16];
    __syncthreads();

    const int j  = t & 31;
    const int og = t >> 5;            // 0..15; outputs o = og + 16k, k=0..4
    float s[5];
    #pragma unroll
    for (int k = 0; k < 5; ++k) s[k] = blds[og + 16*k];
    const f32x4* xrow = (const f32x4*)&xs[j][0];
    #pragma unroll 4
    for (int c4 = 0; c4 < 16; ++c4) {
        const f32x4 xv = xrow[c4];
        #pragma unroll
        for (int k = 0; k < 5; ++k) {
            const f32x4 wv = *(const f32x4*)&Wlds[og + 16*k][c4*4];
            s[k] += wv.x * xv.x;
            s[k] += wv.y * xv.y;
            s[k] += wv.z * xv.z;
            s[k] += wv.w * xv.w;
        }
    }
    const float LOG2E = 1.44269504088896340736f;
    #pragma unroll
    for (int k = 0; k < 5; ++k) {
        int o = og + 16*k;
        if (o < 8) {
            float v = s[k] * LOG2E;
            unsigned short h = bf_hi(v);
            F16[(size_t)(n0+j)*16 + o]     = h;
            F16[(size_t)(n0+j)*16 + 8 + o] = bf_hi(v - bf_f(h));
        } else if (o < 16) {
            float v = s[k];
            unsigned short h = bf_hi(v);
            G16[(size_t)(n0+j)*16 + (o-8)]     = h;
            G16[(size_t)(n0+j)*16 + 8 + (o-8)] = bf_hi(v - bf_f(h));
        } else {
            vb[(size_t)(n0+j)*64 + (o-16)] = s[k];
        }
    }
}

// ---------------------------------------------------------------------------
// Kernel 1: l[n] = sum_m exp2(f[n].g[m]) via MFMA logits, S-pipelined:
// iteration it computes S(it+1) on the MFMA pipe while exp2(S(it)) runs on
// the VALU. m-step 32, B loaded 2 steps ahead.
// ---------------------------------------------------------------------------
__global__ __launch_bounds__(512, 4) void rownorm_kernel(float* __restrict__ ws)
{
    int a, bidx;
    xcd_map(blockIdx.x + (int)gridDim.x * blockIdx.y, a, bidx);   // lin 0..511
    float* base = ws + (size_t)a * WSP;
    const unsigned short* F16 = (const unsigned short*)base;
    const unsigned short* G16 = (const unsigned short*)(base + OFF_G);
    float* vb = base + OFF_T;
    const int n0 = bidx * 32;
    const int t  = threadIdx.x;
    const int w = t >> 6, lane = t & 63, l31 = lane & 31, hi = lane >> 5;

    __shared__ float vbs[32][64];   // staged v rows (in-place overwrite safety)
    __shared__ float lsum[8][32];
    __shared__ float linv[32];

    {   // vb read exactly once -> non-temporal
        const f32x4* vp = (const f32x4*)(vb + (size_t)n0*64);
        f32x4 v = __builtin_nontemporal_load(vp + t);
        *(f32x4*)&vbs[t >> 4][(t & 15) * 4] = v;
    }

    // A fragment: rows n0..n0+31, hi half = fl octet (3-term hi/lo packing)
    const bf16x8 A1 = *(const bf16x8*)(F16 + (size_t)(n0 + l31)*16 + hi*8);
    const bf16x8 z8 = {0,0,0,0,0,0,0,0};
    const bf16x8 A2 = hi ? z8 : A1;      // [fh ; 0]

    const int mb = w * (N/8);
    const int MM = (N/8) - 1;
    bf16x8 B1, B2;
    f32x16 S, sum = ZERO16;

    // prologue: S(0); B(1) in flight
    B1 = *(const bf16x8*)(G16 + (size_t)(mb + l31)*16);
    B2 = *(const bf16x8*)(G16 + (size_t)(mb + l31)*16 + 8);
    S = __builtin_amdgcn_mfma_f32_32x32x16_bf16(A1, B1, ZERO16, 0, 0, 0);
    S = __builtin_amdgcn_mfma_f32_32x32x16_bf16(A2, B2, S, 0, 0, 0);
    B1 = *(const bf16x8*)(G16 + (size_t)(mb + 32 + l31)*16);
    B2 = *(const bf16x8*)(G16 + (size_t)(mb + 32 + l31)*16 + 8);

    for (int it = 0; it < 32; ++it) {
        // S(it+1) on the MFMA pipe (independent of exp2 below)
        f32x16 Sn = __builtin_amdgcn_mfma_f32_32x32x16_bf16(A1, B1, ZERO16, 0, 0, 0);
        Sn = __builtin_amdgcn_mfma_f32_32x32x16_bf16(A2, B2, Sn, 0, 0, 0);
        // B(it+2), wrapped
        {
            const size_t mrow = mb + (((it+2)*32) & MM) + l31;
            B1 = *(const bf16x8*)(G16 + mrow*16);
            B2 = *(const bf16x8*)(G16 + mrow*16 + 8);
        }
        // consume S(it) on the VALU
        #pragma unroll
        for (int r = 0; r < 16; ++r) sum[r] += EXP2(S[r]);
        S = Sn;
    }
    #pragma unroll
    for (int r = 0; r < 16; ++r) {
        float v = sum[r];
        v += __shfl_xor(v, 1, 64);
        v += __shfl_xor(v, 2, 64);
        v += __shfl_xor(v, 4, 64);
        v += __shfl_xor(v, 8, 64);
        v += __shfl_xor(v, 16, 64);
        sum[r] = v;
    }
    if (l31 == 0) {
        #pragma unroll
        for (int r = 0; r < 16; ++r) {
            int n = (r & 3) + 8*(r >> 2) + 4*hi;
            lsum[w][n] = sum[r];
        }
    }
    __syncthreads();
    if (t < 32) {
        float v = 0.f;
        #pragma unroll
        for (int ww = 0; ww < 8; ++ww) v += lsum[ww][t];
        linv[t] = 1.0f / v;
    }
    __syncthreads();

    // emit tiles: position kk holds vt[n0 + sigma(kk)][c]
    if (t < 256) {
        const int c = t & 63, kkg = t >> 6;
        bf16x8 H, L;
        #pragma unroll
        for (int jj = 0; jj < 8; ++jj) {
            int n_rd = (kkg >> 1)*16 + 4*(kkg & 1) + (jj & 3) + 8*((jj >> 2) & 1);
            float v = vbs[n_rd][c] * linv[n_rd];
            unsigned short h = bf_hi(v);
            H[jj] = (short)h;
            L[jj] = (short)bf_hi(v - bf_f(h));
        }
        unsigned short* tile = (unsigned short*)(base + OFF_T) + (size_t)(n0 >> 5) * 4096;
        unsigned short* tp = tile + c*32 + kkg*8;
        *(bf16x8*)tp          = H;
        *(bf16x8*)(tp + 2048) = L;
    }
}

// ---------------------------------------------------------------------------
// Kernel 2: sa[c][m] = sum_n vt[n][c] * exp2(f[n].g[m]).
// Stage-level software pipeline: iteration it holds S(it) (computed in it-1);
// order = {pack kp0 -> PV kp0 -> pack kp1 -> logits(it+1) into S -> PV kp1 ->
// tile prefetch}. exp2/pack of it+1 overlap PV of it; MFMA pipe never waits
// on the VALU chain. p kept per-kp (16 VGPR) so total stays under 256.
// ---------------------------------------------------------------------------
__global__ __launch_bounds__(512, 2) void attn_kernel(
    const float* __restrict__ x1, const float* __restrict__ x2,
    const float* __restrict__ ga1, const float* __restrict__ ga2,
    const float* __restrict__ ws, float* __restrict__ out_)
{
    int a, bidx;
    xcd_map(blockIdx.x + (int)gridDim.x * blockIdx.y, a, bidx);   // lin 0..255
    const float* x = a ? x2 : x1;
    const float gamma = a ? ga2[0] : ga1[0];
    const float* base = ws + (size_t)a * WSP;
    const unsigned short* F16 = (const unsigned short*)base;
    const unsigned short* G16 = (const unsigned short*)(base + OFF_G);
    const unsigned short* tiles = (const unsigned short*)(base + OFF_T);
    float* out = out_ + (size_t)a * ((size_t)64 * N);

    const int m0 = bidx * 64;
    const int t = threadIdx.x;
    const int w = t >> 6, lane = t & 63, l31 = lane & 31, hi = lane >> 5;

    // g fragments for the wave's TWO 32-col m-groups (resident all kernel)
    const bf16x8 z8 = {0,0,0,0,0,0,0,0};
    bf16x8 Bh0, Bl0, Bh1, Bl1;
    {
        const unsigned short* gp0 = G16 + (size_t)(m0 + l31)*16;
        const unsigned short* gp1 = G16 + (size_t)(m0 + 32 + l31)*16;
        Bh0 = *(const bf16x8*)gp0;
        Bl0 = hi ? z8 : *(const bf16x8*)(gp0 + 8);
        Bh1 = *(const bf16x8*)gp1;
        Bl1 = hi ? z8 : *(const bf16x8*)(gp1 + 8);
    }

    f32x16 accA = ZERO16, accB = ZERO16;   // mg0: ct=0, ct=1
    f32x16 accC = ZERO16, accD = ZERO16;   // mg1: ct=0, ct=1

    const int kbeg = w * (N/8);
    const int KM = (N/8) - 1;      // wrap mask within this wave's K-range

    bf16x8 A;                      // single A buffer (load 1 step ahead)
    bf16x8 AH[4], AL[4];           // PV tiles for the CURRENT iteration
    f32x16 S0, S1;

    // prologue: S(0) from A(0); A(1) in flight; tiles(0)
    A = *(const bf16x8*)(F16 + (size_t)(kbeg + l31)*16 + hi*8);
    S0 = __builtin_amdgcn_mfma_f32_32x32x16_bf16(A, Bh0, ZERO16, 0, 0, 0);
    S1 = __builtin_amdgcn_mfma_f32_32x32x16_bf16(A, Bh1, ZERO16, 0, 0, 0);
    S0 = __builtin_amdgcn_mfma_f32_32x32x16_bf16(A, Bl0, S0, 0, 0, 0);
    S1 = __builtin_amdgcn_mfma_f32_32x32x16_bf16(A, Bl1, S1, 0, 0, 0);
    A = *(const bf16x8*)(F16 + (size_t)(kbeg + 32 + l31)*16 + hi*8);
    {
        const unsigned short* tb = tiles + (size_t)(kbeg >> 5) * 4096;
        #pragma unroll
        for (int kp = 0; kp < 2; ++kp)
            #pragma unroll
            for (int ct = 0; ct < 2; ++ct) {
                const unsigned short* tc = tb + (ct*32 + l31)*32 + kp*16 + hi*8;
                AH[kp*2+ct] = *(const bf16x8*)tc;
                AL[kp*2+ct] = *(const bf16x8*)(tc + 2048);
            }
    }

    union BU { bf16x8 v; unsigned u[4]; };

    for (int it = 0; it < 32; ++it) {
        __builtin_amdgcn_s_setprio(1);
        // ---- kp = 0: pack from S(it)[0..7], then PV ----
        {
            BU pH0, pL0, pH1, pL1;
            #pragma unroll
            for (int d = 0; d < 4; ++d) {
                float q0 = EXP2(S0[2*d]);
                float q1 = EXP2(S0[2*d + 1]);
                unsigned i0 = __float_as_uint(q0), i1 = __float_as_uint(q1);
                pH0.u[d] = pack_hi16(i1, i0);
                unsigned r0 = __float_as_uint(q0 - __uint_as_float(i0 & 0xffff0000u));
                unsigned r1 = __float_as_uint(q1 - __uint_as_float(i1 & 0xffff0000u));
                pL0.u[d] = pack_hi16(r1, r0);
                float q2 = EXP2(S1[2*d]);
                float q3 = EXP2(S1[2*d + 1]);
                unsigned i2 = __float_as_uint(q2), i3 = __float_as_uint(q3);
                pH1.u[d] = pack_hi16(i3, i2);
                unsigned r2 = __float_as_uint(q2 - __uint_as_float(i2 & 0xffff0000u));
                unsigned r3 = __float_as_uint(q3 - __uint_as_float(i3 & 0xffff0000u));
                pL1.u[d] = pack_hi16(r3, r2);
            }
            accA = __builtin_amdgcn_mfma_f32_32x32x16_bf16(AH[0], pH0.v, accA, 0, 0, 0);
            accC = __builtin_amdgcn_mfma_f32_32x32x16_bf16(AH[0], pH1.v, accC, 0, 0, 0);
            accA = __builtin_amdgcn_mfma_f32_32x32x16_bf16(AH[0], pL0.v, accA, 0, 0, 0);
            accC = __builtin_amdgcn_mfma_f32_32x32x16_bf16(AH[0], pL1.v, accC, 0, 0, 0);
            accA = __builtin_amdgcn_mfma_f32_32x32x16_bf16(AL[0], pH0.v, accA, 0, 0, 0);
            accC = __builtin_amdgcn_mfma_f32_32x32x16_bf16(AL[0], pH1.v, accC, 0, 0, 0);
            accB = __builtin_amdgcn_mfma_f32_32x32x16_bf16(AH[1], pH0.v, accB, 0, 0, 0);
            accD = __builtin_amdgcn_mfma_f32_32x32x16_bf16(AH[1], pH1.v, accD, 0, 0, 0);
            accB = __builtin_amdgcn_mfma_f32_32x32x16_bf16(AH[1], pL0.v, accB, 0, 0, 0);
            accD = __builtin_amdgcn_mfma_f32_32x32x16_bf16(AH[1], pL1.v, accD, 0, 0, 0);
            accB = __builtin_amdgcn_mfma_f32_32x32x16_bf16(AL[1], pH0.v, accB, 0, 0, 0);
            accD = __builtin_amdgcn_mfma_f32_32x32x16_bf16(AL[1], pH1.v, accD, 0, 0, 0);
        }
        // ---- kp = 1: pack from S(it)[8..15]; then logits(it+1); then PV ----
        {
            BU pH0, pL0, pH1, pL1;
            #pragma unroll
            for (int d = 0; d < 4; ++d) {
                float q0 = EXP2(S0[8 + 2*d]);
                float q1 = EXP2(S0[8 + 2*d + 1]);
                unsigned i0 = __float_as_uint(q0), i1 = __float_as_uint(q1);
                pH0.u[d] = pack_hi16(i1, i0);
                unsigned r0 = __float_as_uint(q0 - __uint_as_float(i0 & 0xffff0000u));
                unsigned r1 = __float_as_uint(q1 - __uint_as_float(i1 & 0xffff0000u));
                pL0.u[d] = pack_hi16(r1, r0);
                float q2 = EXP2(S1[8 + 2*d]);
                float q3 = EXP2(S1[8 + 2*d + 1]);
                unsigned i2 = __float_as_uint(q2), i3 = __float_as_uint(q3);
                pH1.u[d] = pack_hi16(i3, i2);
                unsigned r2 = __float_as_uint(q2 - __uint_as_float(i2 & 0xffff0000u));
                unsigned r3 = __float_as_uint(q3 - __uint_as_float(i3 & 0xffff0000u));
                pL1.u[d] = pack_hi16(r3, r2);
            }
            // logits for it+1 (S regs dead after the packs above -> reused)
            S0 = __builtin_amdgcn_mfma_f32_32x32x16_bf16(A, Bh0, ZERO16, 0, 0, 0);
            S1 = __builtin_amdgcn_mfma_f32_32x32x16_bf16(A, Bh1, ZERO16, 0, 0, 0);
            S0 = __builtin_amdgcn_mfma_f32_32x32x16_bf16(A, Bl0, S0, 0, 0, 0);
            S1 = __builtin_amdgcn_mfma_f32_32x32x16_bf16(A, Bl1, S1, 0, 0, 0);
            // A for it+2 (wraps harmlessly)
            A = *(const bf16x8*)(F16 + (size_t)(kbeg + (((it+2)*32) & KM) + l31)*16 + hi*8);
            // PV kp1 (covers the logit MFMA latency)
            accA = __builtin_amdgcn_mfma_f32_32x32x16_bf16(AH[2], pH0.v, accA, 0, 0, 0);
            accC = __builtin_amdgcn_mfma_f32_32x32x16_bf16(AH[2], pH1.v, accC, 0, 0, 0);
            accA = __builtin_amdgcn_mfma_f32_32x32x16_bf16(AH[2], pL0.v, accA, 0, 0, 0);
            accC = __builtin_amdgcn_mfma_f32_32x32x16_bf16(AH[2], pL1.v, accC, 0, 0, 0);
            accA = __builtin_amdgcn_mfma_f32_32x32x16_bf16(AL[2], pH0.v, accA, 0, 0, 0);
            accC = __builtin_amdgcn_mfma_f32_32x32x16_bf16(AL[2], pH1.v, accC, 0, 0, 0);
            accB = __builtin_amdgcn_mfma_f32_32x32x16_bf16(AH[3], pH0.v, accB, 0, 0, 0);
            accD = __builtin_amdgcn_mfma_f32_32x32x16_bf16(AH[3], pH1.v, accD, 0, 0, 0);
            accB = __builtin_amdgcn_mfma_f32_32x32x16_bf16(AH[3], pL0.v, accB, 0, 0, 0);
            accD = __builtin_amdgcn_mfma_f32_32x32x16_bf16(AH[3], pL1.v, accD, 0, 0, 0);
            accB = __builtin_amdgcn_mfma_f32_32x32x16_bf16(AL[3], pH0.v, accB, 0, 0, 0);
            accD = __builtin_amdgcn_mfma_f32_32x32x16_bf16(AL[3], pH1.v, accD, 0, 0, 0);
        }
        __builtin_amdgcn_s_setprio(0);
        // tiles for it+1 (issued after last use of AH/AL)
        {
            const unsigned short* tb = tiles
                + (size_t)((kbeg + (((it+1)*32) & KM)) >> 5) * 4096;
            #pragma unroll
            for (int kp = 0; kp < 2; ++kp)
                #pragma unroll
                for (int ct = 0; ct < 2; ++ct) {
                    const unsigned short* tc = tb + (ct*32 + l31)*32 + kp*16 + hi*8;
                    AH[kp*2+ct] = *(const bf16x8*)tc;
                    AL[kp*2+ct] = *(const bf16x8*)(tc + 2048);
                }
        }
    }

    // cross-wave (K-split) reduction over 8 waves; 64c x 64m block tile
    __shared__ float red[64][65];
    for (int ww = 0; ww < 8; ++ww) {
        if (w == ww) {
            #pragma unroll
            for (int mg = 0; mg < 2; ++mg)
                #pragma unroll
                for (int ct = 0; ct < 2; ++ct) {
                    const f32x16& Ac = mg ? (ct ? accD : accC) : (ct ? accB : accA);
                    #pragma unroll
                    for (int r = 0; r < 16; ++r) {
                        int c = ct*32 + (r & 3) + 8*(r >> 2) + 4*hi;   // C/D row map
                        int m = mg*32 + l31;
                        if (ww == 0) red[c][m]  = Ac[r];
                        else         red[c][m] += Ac[r];
                    }
                }
        }
        __syncthreads();
    }
    #pragma unroll
    for (int i = 0; i < 8; ++i) {
        int e = t + 512*i;
        int c = e >> 6, m = e & 63;
        size_t gi = (size_t)c*N + m0 + m;
        float xv = __builtin_nontemporal_load(x + gi);
        __builtin_nontemporal_store(gamma * red[c][m] + xv, out + gi);
    }
}

// ---------------------------------------------------------------------------
extern "C" void kernel_launch(void* const* d_in, const int* in_sizes, int n_in,
                              void* d_out, int out_size, void* d_ws, size_t ws_size,
                              hipStream_t stream)
{
    (void)in_sizes; (void)n_in; (void)out_size; (void)ws_size;
    const float* x1  = (const float*)d_in[0];
    const float* x2  = (const float*)d_in[1];
    const float* Wf  = (const float*)d_in[2];
    const float* bf  = (const float*)d_in[3];
    const float* Wg  = (const float*)d_in[4];
    const float* bg  = (const float*)d_in[5];
    const float* Wh1 = (const float*)d_in[6];
    const float* bh1 = (const float*)d_in[7];
    const float* Wh2 = (const float*)d_in[8];
    const float* bh2 = (const float*)d_in[9];
    const float* g1  = (const float*)d_in[10];
    const float* g2  = (const float*)d_in[11];
    float* out = (float*)d_out;
    float* ws  = (float*)d_ws;

    prep_kernel   <<<dim3(N/32, 2), dim3(512), 0, stream>>>(x1,x2,Wf,bf,Wg,bg,Wh1,bh1,Wh2,bh2,ws);
    rownorm_kernel<<<dim3(N/32, 2), dim3(512), 0, stream>>>(ws);
    attn_kernel   <<<dim3(N/64, 2), dim3(512), 0, stream>>>(x1,x2,g1,g2,ws,out);
}